// Round 1
// baseline (2499.826 us; speedup 1.0000x reference)
//
#include <hip/hip_runtime.h>
#include <hip/hip_bf16.h>

#define WAVE 64

// ---------------- degree / normalization ----------------
__global__ void deg_init_kernel(float* __restrict__ deg, int n) {
    int i = blockIdx.x * blockDim.x + threadIdx.x;
    if (i < n) deg[i] = 1.0f;  // self-loop
}

__global__ void deg_count_kernel(const int* __restrict__ dst, float* __restrict__ deg, int E) {
    int e = blockIdx.x * blockDim.x + threadIdx.x;
    if (e < E) atomicAdd(&deg[dst[e]], 1.0f);
}

__global__ void dinv_kernel(float* __restrict__ deg, int n) {
    int i = blockIdx.x * blockDim.x + threadIdx.x;
    if (i < n) {
        float d = deg[i];
        deg[i] = d > 0.f ? rsqrtf(d) : 0.f;
    }
}

// ---------------- GEMM1: [N,256] @ [256,128] ----------------
__global__ __launch_bounds__(256) void gemm1_kernel(const float* __restrict__ x,
                                                    const float* __restrict__ W,
                                                    float* __restrict__ out, int nrows) {
    __shared__ float Wl[128 * 128];  // 64 KiB: half of W1 (K-chunked)
    int r = threadIdx.x >> 3;        // 0..31 rows per block
    int cl = threadIdx.x & 7;        // 8 threads per row
    long row = (long)blockIdx.x * 32 + r;
    float acc[16];
#pragma unroll
    for (int j = 0; j < 16; ++j) acc[j] = 0.f;

    for (int kc = 0; kc < 2; ++kc) {
        __syncthreads();
        for (int i = threadIdx.x; i < 128 * 128; i += 256) Wl[i] = W[kc * 128 * 128 + i];
        __syncthreads();
        if (row < nrows) {
            const float* xr = x + row * 256 + kc * 128;
            for (int k = 0; k < 128; k += 4) {
                float4 xv = *reinterpret_cast<const float4*>(xr + k);
#pragma unroll
                for (int kk = 0; kk < 4; ++kk) {
                    float xs = (&xv.x)[kk];
                    const float* wr = &Wl[(k + kk) * 128 + cl];
#pragma unroll
                    for (int j = 0; j < 16; ++j) acc[j] = fmaf(xs, wr[8 * j], acc[j]);
                }
            }
        }
    }
    if (row < nrows) {
        float* orow = out + row * 128 + cl;
#pragma unroll
        for (int j = 0; j < 16; ++j) orow[8 * j] = acc[j];
    }
}

// ---------------- GEMM2: [N,128] @ [128,64] ----------------
__global__ __launch_bounds__(256) void gemm2_kernel(const float* __restrict__ h,
                                                    const float* __restrict__ W,
                                                    float* __restrict__ out, int nrows) {
    __shared__ float Wl[128 * 64];  // 32 KiB: all of W2
    for (int i = threadIdx.x; i < 128 * 64; i += 256) Wl[i] = W[i];
    __syncthreads();
    int r = threadIdx.x >> 3;
    int cl = threadIdx.x & 7;
    long row = (long)blockIdx.x * 32 + r;
    if (row >= nrows) return;
    const float* hr = h + row * 128;
    float acc[8];
#pragma unroll
    for (int j = 0; j < 8; ++j) acc[j] = 0.f;
    for (int k = 0; k < 128; k += 4) {
        float4 xv = *reinterpret_cast<const float4*>(hr + k);
#pragma unroll
        for (int kk = 0; kk < 4; ++kk) {
            float xs = (&xv.x)[kk];
            const float* wr = &Wl[(k + kk) * 64 + cl];
#pragma unroll
            for (int j = 0; j < 8; ++j) acc[j] = fmaf(xs, wr[8 * j], acc[j]);
        }
    }
    float* orow = out + row * 64 + cl;
#pragma unroll
    for (int j = 0; j < 8; ++j) orow[8 * j] = acc[j];
}

// ---------------- self-loop init: agg[n] = dinv[n]^2 * h[n] ----------------
template <int LOGF>
__global__ void self_init_kernel(const float* __restrict__ h, const float* __restrict__ dinv,
                                 float* __restrict__ agg, long total) {
    long i = (long)blockIdx.x * blockDim.x + threadIdx.x;
    if (i >= total) return;
    int node = (int)(i >> LOGF);
    float w = dinv[node];
    agg[i] = w * w * h[i];
}

// ---------------- edge scatter-add: one wave per edge ----------------
template <int F>
__global__ __launch_bounds__(256) void edge_agg_kernel(const float* __restrict__ h,
                                                       const float* __restrict__ dinv,
                                                       const int* __restrict__ src,
                                                       const int* __restrict__ dst,
                                                       float* __restrict__ agg, int E) {
    int wid = (int)(((long)blockIdx.x * blockDim.x + threadIdx.x) >> 6);
    int lane = threadIdx.x & 63;
    if (wid >= E) return;
    int s = src[wid];
    int d = dst[wid];
    float w = dinv[s] * dinv[d];
    const float* hs = h + (size_t)s * F;
    float* ad = agg + (size_t)d * F;
#pragma unroll
    for (int f = lane; f < F; f += WAVE) atomicAdd(&ad[f], w * hs[f]);
}

// ---------------- bias + relu (in place) ----------------
__global__ void bias_relu_kernel(float* __restrict__ a, const float* __restrict__ b, long total) {
    long i = (long)blockIdx.x * blockDim.x + threadIdx.x;
    if (i >= total) return;
    int f = (int)(i & 127);
    a[i] = fmaxf(a[i] + b[f], 0.f);
}

// ---------------- bias + log_softmax over 64 cols: one wave per row ----------------
__global__ __launch_bounds__(256) void logsoftmax_kernel(float* __restrict__ out,
                                                         const float* __restrict__ b, int n) {
    int wid = (int)(((long)blockIdx.x * blockDim.x + threadIdx.x) >> 6);
    int lane = threadIdx.x & 63;
    if (wid >= n) return;
    float v = out[(size_t)wid * 64 + lane] + b[lane];
    float m = v;
#pragma unroll
    for (int o = 32; o; o >>= 1) m = fmaxf(m, __shfl_xor(m, o, WAVE));
    float e = __expf(v - m);
    float s = e;
#pragma unroll
    for (int o = 32; o; o >>= 1) s += __shfl_xor(s, o, WAVE);
    out[(size_t)wid * 64 + lane] = v - m - __logf(s);
}

extern "C" void kernel_launch(void* const* d_in, const int* in_sizes, int n_in,
                              void* d_out, int out_size, void* d_ws, size_t ws_size,
                              hipStream_t stream) {
    const float* x  = (const float*)d_in[0];
    const float* W1 = (const float*)d_in[1];
    const float* b1 = (const float*)d_in[2];
    const float* W2 = (const float*)d_in[3];
    const float* b2 = (const float*)d_in[4];
    const int* edge = (const int*)d_in[5];

    const int N = in_sizes[0] / 256;
    const int E = in_sizes[5] / 2;
    const int* src = edge;
    const int* dst = edge + E;

    float* ws = (float*)d_ws;
    // layout: dinv[N] | h_lin[N*128] (reused as h2_lin[N*64]) | agg1[N*128]
    size_t offD = 0;
    size_t offH = (size_t)((N + 255) / 256) * 256;
    size_t offA = offH + (size_t)N * 128;
    float* dinv = ws + offD;
    float* hlin = ws + offH;   // layer-1 linear output, later reused for layer-2 linear
    float* agg1 = ws + offA;   // layer-1 aggregate (relu'd in place)
    float* outp = (float*)d_out;

    const int TB = 256;
    // 1) degree with self-loop, then dinv = rsqrt(deg)
    deg_init_kernel<<<(N + TB - 1) / TB, TB, 0, stream>>>(dinv, N);
    deg_count_kernel<<<(E + TB - 1) / TB, TB, 0, stream>>>(dst, dinv, E);
    dinv_kernel<<<(N + TB - 1) / TB, TB, 0, stream>>>(dinv, N);

    // 2) h = x @ W1
    gemm1_kernel<<<(N + 31) / 32, TB, 0, stream>>>(x, W1, hlin, N);

    // 3) agg1 = selfloop + scatter-add over edges
    long tot1 = (long)N * 128;
    self_init_kernel<7><<<(tot1 + TB - 1) / TB, TB, 0, stream>>>(hlin, dinv, agg1, tot1);
    edge_agg_kernel<128><<<(E + 3) / 4, TB, 0, stream>>>(hlin, dinv, src, dst, agg1, E);

    // 4) h1 = relu(agg1 + b1), in place
    bias_relu_kernel<<<(tot1 + TB - 1) / TB, TB, 0, stream>>>(agg1, b1, tot1);

    // 5) h2lin = h1 @ W2  (reuse hlin buffer)
    gemm2_kernel<<<(N + 31) / 32, TB, 0, stream>>>(agg1, W2, hlin, N);

    // 6) agg2 (into d_out) = selfloop + scatter-add
    long tot2 = (long)N * 64;
    self_init_kernel<6><<<(tot2 + TB - 1) / TB, TB, 0, stream>>>(hlin, dinv, outp, tot2);
    edge_agg_kernel<64><<<(E + 3) / 4, TB, 0, stream>>>(hlin, dinv, src, dst, outp, E);

    // 7) out = log_softmax(agg2 + b2)
    logsoftmax_kernel<<<(N + 3) / 4, TB, 0, stream>>>(outp, b2, N);
}

// Round 2
// 1265.577 us; speedup vs baseline: 1.9752x; 1.9752x over previous
//
#include <hip/hip_runtime.h>
#include <hip/hip_bf16.h>

#define WAVE 64

// ---------------- zero int buffer ----------------
__global__ void zero_int_kernel(int* __restrict__ p, int n) {
    int i = blockIdx.x * blockDim.x + threadIdx.x;
    if (i < n) p[i] = 0;
}

// ---------------- in-degree count ----------------
__global__ void deg_count_kernel(const int* __restrict__ dst, int* __restrict__ cnt, int E) {
    int e = blockIdx.x * blockDim.x + threadIdx.x;
    if (e < E) atomicAdd(&cnt[dst[e]], 1);
}

// ---------------- dinv = rsqrt(1 + indeg) ----------------
__global__ void dinv_kernel(const int* __restrict__ cnt, float* __restrict__ dinv, int n) {
    int i = blockIdx.x * blockDim.x + threadIdx.x;
    if (i < n) dinv[i] = rsqrtf(1.0f + (float)cnt[i]);
}

// ---------------- exclusive scan (3-kernel, N<=131072) ----------------
#define SCAN_B 256
__global__ void scan_blocks_kernel(const int* __restrict__ cnt, int* __restrict__ excl,
                                   int* __restrict__ partial, int n) {
    __shared__ int sh[SCAN_B];
    int tid = threadIdx.x;
    int i = blockIdx.x * SCAN_B + tid;
    int v = (i < n) ? cnt[i] : 0;
    sh[tid] = v;
    __syncthreads();
#pragma unroll
    for (int o = 1; o < SCAN_B; o <<= 1) {
        int t = (tid >= o) ? sh[tid - o] : 0;
        __syncthreads();
        sh[tid] += t;
        __syncthreads();
    }
    if (i < n) excl[i] = sh[tid] - v;
    if (tid == SCAN_B - 1) partial[blockIdx.x] = sh[tid];
}

__global__ void scan_partials_kernel(int* __restrict__ partial, int nb) {
    __shared__ int sh[512];
    int tid = threadIdx.x;
    int v = (tid < nb) ? partial[tid] : 0;
    sh[tid] = v;
    __syncthreads();
#pragma unroll
    for (int o = 1; o < 512; o <<= 1) {
        int t = (tid >= o) ? sh[tid - o] : 0;
        __syncthreads();
        sh[tid] += t;
        __syncthreads();
    }
    if (tid < nb) partial[tid] = sh[tid] - v;
}

__global__ void add_offsets_kernel(int* __restrict__ excl, const int* __restrict__ partial, int n) {
    int i = blockIdx.x * SCAN_B + threadIdx.x;
    if (i < n) excl[i] += partial[blockIdx.x];
}

// ---------------- counting-sort placement ----------------
__global__ void place_kernel(const int* __restrict__ src, const int* __restrict__ dst,
                             int* __restrict__ cursor, int* __restrict__ sorted_src, int E) {
    int e = blockIdx.x * blockDim.x + threadIdx.x;
    if (e < E) {
        int d = dst[e];
        int p = atomicAdd(&cursor[d], 1);
        sorted_src[p] = src[e];
    }
}

// ---------------- GEMM1: [N,256] @ [256,128] ----------------
__global__ __launch_bounds__(256) void gemm1_kernel(const float* __restrict__ x,
                                                    const float* __restrict__ W,
                                                    float* __restrict__ out, int nrows) {
    __shared__ float Wl[128 * 128];
    int r = threadIdx.x >> 3;
    int cl = threadIdx.x & 7;
    long row = (long)blockIdx.x * 32 + r;
    float acc[16];
#pragma unroll
    for (int j = 0; j < 16; ++j) acc[j] = 0.f;

    for (int kc = 0; kc < 2; ++kc) {
        __syncthreads();
        for (int i = threadIdx.x; i < 128 * 128; i += 256) Wl[i] = W[kc * 128 * 128 + i];
        __syncthreads();
        if (row < nrows) {
            const float* xr = x + row * 256 + kc * 128;
            for (int k = 0; k < 128; k += 4) {
                float4 xv = *reinterpret_cast<const float4*>(xr + k);
#pragma unroll
                for (int kk = 0; kk < 4; ++kk) {
                    float xs = (&xv.x)[kk];
                    const float* wr = &Wl[(k + kk) * 128 + cl];
#pragma unroll
                    for (int j = 0; j < 16; ++j) acc[j] = fmaf(xs, wr[8 * j], acc[j]);
                }
            }
        }
    }
    if (row < nrows) {
        float* orow = out + row * 128 + cl;
#pragma unroll
        for (int j = 0; j < 16; ++j) orow[8 * j] = acc[j];
    }
}

// ---------------- GEMM2: [N,128] @ [128,64] ----------------
__global__ __launch_bounds__(256) void gemm2_kernel(const float* __restrict__ h,
                                                    const float* __restrict__ W,
                                                    float* __restrict__ out, int nrows) {
    __shared__ float Wl[128 * 64];
    for (int i = threadIdx.x; i < 128 * 64; i += 256) Wl[i] = W[i];
    __syncthreads();
    int r = threadIdx.x >> 3;
    int cl = threadIdx.x & 7;
    long row = (long)blockIdx.x * 32 + r;
    if (row >= nrows) return;
    const float* hr = h + row * 128;
    float acc[8];
#pragma unroll
    for (int j = 0; j < 8; ++j) acc[j] = 0.f;
    for (int k = 0; k < 128; k += 4) {
        float4 xv = *reinterpret_cast<const float4*>(hr + k);
#pragma unroll
        for (int kk = 0; kk < 4; ++kk) {
            float xs = (&xv.x)[kk];
            const float* wr = &Wl[(k + kk) * 64 + cl];
#pragma unroll
            for (int j = 0; j < 8; ++j) acc[j] = fmaf(xs, wr[8 * j], acc[j]);
        }
    }
    float* orow = out + row * 64 + cl;
#pragma unroll
    for (int j = 0; j < 8; ++j) orow[8 * j] = acc[j];
}

// ---------------- layer-1 pull aggregation, fused bias+relu ----------------
// one wave per destination node; lane owns features (lane, lane+64)
__global__ __launch_bounds__(256) void agg1_kernel(const float* __restrict__ h,
                                                   const float* __restrict__ dinv,
                                                   const int* __restrict__ srt,
                                                   const int* __restrict__ rowend,
                                                   const float* __restrict__ bias,
                                                   float* __restrict__ out, int n) {
    int wid = (int)(((long)blockIdx.x * blockDim.x + threadIdx.x) >> 6);
    int lane = threadIdx.x & 63;
    if (wid >= n) return;
    int start = wid ? rowend[wid - 1] : 0;
    int end = rowend[wid];
    float wd = dinv[wid];
    const float* hn = h + (size_t)wid * 128;
    float a0 = wd * wd * hn[lane];
    float a1 = wd * wd * hn[lane + 64];
    for (int e = start; e < end; ++e) {
        int s = srt[e];
        float w = wd * dinv[s];
        const float* hs = h + (size_t)s * 128;
        a0 = fmaf(w, hs[lane], a0);
        a1 = fmaf(w, hs[lane + 64], a1);
    }
    out[(size_t)wid * 128 + lane] = fmaxf(a0 + bias[lane], 0.f);
    out[(size_t)wid * 128 + lane + 64] = fmaxf(a1 + bias[lane + 64], 0.f);
}

// ---------------- layer-2 pull aggregation, fused bias + log_softmax ----------------
__global__ __launch_bounds__(256) void agg2_ls_kernel(const float* __restrict__ h,
                                                      const float* __restrict__ dinv,
                                                      const int* __restrict__ srt,
                                                      const int* __restrict__ rowend,
                                                      const float* __restrict__ bias,
                                                      float* __restrict__ out, int n) {
    int wid = (int)(((long)blockIdx.x * blockDim.x + threadIdx.x) >> 6);
    int lane = threadIdx.x & 63;
    if (wid >= n) return;
    int start = wid ? rowend[wid - 1] : 0;
    int end = rowend[wid];
    float wd = dinv[wid];
    float a = wd * wd * h[(size_t)wid * 64 + lane];
    for (int e = start; e < end; ++e) {
        int s = srt[e];
        a = fmaf(wd * dinv[s], h[(size_t)s * 64 + lane], a);
    }
    float v = a + bias[lane];
    float m = v;
#pragma unroll
    for (int o = 32; o; o >>= 1) m = fmaxf(m, __shfl_xor(m, o, WAVE));
    float ex = __expf(v - m);
    float sum = ex;
#pragma unroll
    for (int o = 32; o; o >>= 1) sum += __shfl_xor(sum, o, WAVE);
    out[(size_t)wid * 64 + lane] = v - m - __logf(sum);
}

extern "C" void kernel_launch(void* const* d_in, const int* in_sizes, int n_in,
                              void* d_out, int out_size, void* d_ws, size_t ws_size,
                              hipStream_t stream) {
    const float* x  = (const float*)d_in[0];
    const float* W1 = (const float*)d_in[1];
    const float* b1 = (const float*)d_in[2];
    const float* W2 = (const float*)d_in[3];
    const float* b2 = (const float*)d_in[4];
    const int* edge = (const int*)d_in[5];

    const int N = in_sizes[0] / 256;
    const int E = in_sizes[5] / 2;
    const int* src = edge;
    const int* dst = edge + E;

    // ws layout (4B units): cnt[N] | cursor[N] | partial[512] | dinv[N] | sorted[E] | hlin[N*128] | agg1[N*128]
    int*   cnt    = (int*)d_ws;
    int*   cursor = cnt + N;
    int*   partial = cursor + N;
    float* dinv   = (float*)(partial + 512);
    int*   sorted = (int*)(dinv + N);
    float* hlin   = (float*)(sorted + E);
    float* agg1   = hlin + (size_t)N * 128;
    float* outp   = (float*)d_out;

    const int TB = 256;
    const int nScanBlocks = (N + SCAN_B - 1) / SCAN_B;

    // 1) in-degree counts, dinv
    zero_int_kernel<<<(N + TB - 1) / TB, TB, 0, stream>>>(cnt, N);
    deg_count_kernel<<<(E + TB - 1) / TB, TB, 0, stream>>>(dst, cnt, E);
    dinv_kernel<<<(N + TB - 1) / TB, TB, 0, stream>>>(cnt, dinv, N);

    // 2) CSR build: exclusive scan into cursor, then counting-sort placement.
    //    After placement, cursor[n] == row_end(n); row_start(n) = cursor[n-1].
    scan_blocks_kernel<<<nScanBlocks, SCAN_B, 0, stream>>>(cnt, cursor, partial, N);
    scan_partials_kernel<<<1, 512, 0, stream>>>(partial, nScanBlocks);
    add_offsets_kernel<<<nScanBlocks, SCAN_B, 0, stream>>>(cursor, partial, N);
    place_kernel<<<(E + TB - 1) / TB, TB, 0, stream>>>(src, dst, cursor, sorted, E);

    // 3) h = x @ W1
    gemm1_kernel<<<(N + 31) / 32, TB, 0, stream>>>(x, W1, hlin, N);

    // 4) agg1 = relu(D^-1/2 A_hat D^-1/2 h + b1)   (pull, fused)
    agg1_kernel<<<(N * 64 + TB - 1) / TB, TB, 0, stream>>>(hlin, dinv, sorted, cursor, b1, agg1, N);

    // 5) h2 = agg1 @ W2  (reuse hlin)
    gemm2_kernel<<<(N + 31) / 32, TB, 0, stream>>>(agg1, W2, hlin, N);

    // 6) out = log_softmax(D^-1/2 A_hat D^-1/2 h2 + b2)  (pull, fused)
    agg2_ls_kernel<<<(N * 64 + TB - 1) / TB, TB, 0, stream>>>(hlin, dinv, sorted, cursor, b2, outp, N);
}

// Round 3
// 863.384 us; speedup vs baseline: 2.8954x; 1.4658x over previous
//
#include <hip/hip_runtime.h>
#include <hip/hip_bf16.h>

#define WAVE 64
typedef unsigned int uint32;

// ---- bf16 helpers (packed pair in a uint32: low ushort = even feature) ----
__device__ inline float bf16lo(uint32 u) { return __uint_as_float(u << 16); }
__device__ inline float bf16hi(uint32 u) { return __uint_as_float(u & 0xffff0000u); }
__device__ inline uint32 f2bf(float f) {  // round-to-nearest-even
    union { float f; uint32 u; } a; a.f = f;
    uint32 u = a.u;
    u += 0x7fffu + ((u >> 16) & 1u);
    return u >> 16;
}
__device__ inline uint32 packbf(float lo, float hi) { return f2bf(lo) | (f2bf(hi) << 16); }

// ---------------- zero int buffer ----------------
__global__ void zero_int_kernel(int* __restrict__ p, int n) {
    int i = blockIdx.x * blockDim.x + threadIdx.x;
    if (i < n) p[i] = 0;
}

// ---------------- in-degree count ----------------
__global__ void deg_count_kernel(const int* __restrict__ dst, int* __restrict__ cnt, int E) {
    int e = blockIdx.x * blockDim.x + threadIdx.x;
    if (e < E) atomicAdd(&cnt[dst[e]], 1);
}

// ---------------- dinv = rsqrt(1 + indeg) ----------------
__global__ void dinv_kernel(const int* __restrict__ cnt, float* __restrict__ dinv, int n) {
    int i = blockIdx.x * blockDim.x + threadIdx.x;
    if (i < n) dinv[i] = rsqrtf(1.0f + (float)cnt[i]);
}

// ---------------- exclusive scan (3-kernel, N<=131072) ----------------
#define SCAN_B 256
__global__ void scan_blocks_kernel(const int* __restrict__ cnt, int* __restrict__ excl,
                                   int* __restrict__ partial, int n) {
    __shared__ int sh[SCAN_B];
    int tid = threadIdx.x;
    int i = blockIdx.x * SCAN_B + tid;
    int v = (i < n) ? cnt[i] : 0;
    sh[tid] = v;
    __syncthreads();
#pragma unroll
    for (int o = 1; o < SCAN_B; o <<= 1) {
        int t = (tid >= o) ? sh[tid - o] : 0;
        __syncthreads();
        sh[tid] += t;
        __syncthreads();
    }
    if (i < n) excl[i] = sh[tid] - v;
    if (tid == SCAN_B - 1) partial[blockIdx.x] = sh[tid];
}

__global__ void scan_partials_kernel(int* __restrict__ partial, int nb) {
    __shared__ int sh[512];
    int tid = threadIdx.x;
    int v = (tid < nb) ? partial[tid] : 0;
    sh[tid] = v;
    __syncthreads();
#pragma unroll
    for (int o = 1; o < 512; o <<= 1) {
        int t = (tid >= o) ? sh[tid - o] : 0;
        __syncthreads();
        sh[tid] += t;
        __syncthreads();
    }
    if (tid < nb) partial[tid] = sh[tid] - v;
}

__global__ void add_offsets_kernel(int* __restrict__ excl, const int* __restrict__ partial, int n) {
    int i = blockIdx.x * SCAN_B + threadIdx.x;
    if (i < n) excl[i] += partial[blockIdx.x];
}

// ---------------- counting-sort placement ----------------
__global__ void place_kernel(const int* __restrict__ src, const int* __restrict__ dst,
                             int* __restrict__ cursor, int* __restrict__ sorted_src, int E) {
    int e = blockIdx.x * blockDim.x + threadIdx.x;
    if (e < E) {
        int d = dst[e];
        int p = atomicAdd(&cursor[d], 1);
        sorted_src[p] = src[e];
    }
}

// ---------------- GEMM1: [N,256]fp32 @ [256,128] -> bf16 scaled by dinv ----------------
// block: 64 rows; thread: 2 rows x 16 cols (cols = cl*4 + 32g + jj), conflict-free b128 W reads
__global__ __launch_bounds__(256) void gemm1_kernel(const float* __restrict__ x,
                                                    const float* __restrict__ W,
                                                    const float* __restrict__ dinv,
                                                    uint32* __restrict__ hout,  // N x 64 uints
                                                    int nrows) {
    __shared__ float Wl[128 * 128];
    int tid = threadIdx.x;
    int rg = tid >> 3, cl = tid & 7;
    int row0 = blockIdx.x * 64 + rg * 2;
    int row1 = row0 + 1;
    float acc0[16], acc1[16];
#pragma unroll
    for (int j = 0; j < 16; ++j) { acc0[j] = 0.f; acc1[j] = 0.f; }

    for (int kc = 0; kc < 2; ++kc) {
        __syncthreads();
        const float4* Wg = (const float4*)(W + kc * 128 * 128);
        float4* Wl4 = (float4*)Wl;
        for (int i = tid; i < 128 * 128 / 4; i += 256) Wl4[i] = Wg[i];
        __syncthreads();
        bool v0 = row0 < nrows, v1 = row1 < nrows;
        const float* xr0 = x + (size_t)row0 * 256 + kc * 128;
        const float* xr1 = x + (size_t)row1 * 256 + kc * 128;
        for (int k4 = 0; k4 < 128; k4 += 4) {
            float4 xv0 = v0 ? *(const float4*)(xr0 + k4) : make_float4(0, 0, 0, 0);
            float4 xv1 = v1 ? *(const float4*)(xr1 + k4) : make_float4(0, 0, 0, 0);
#pragma unroll
            for (int kk = 0; kk < 4; ++kk) {
                const float* wr = &Wl[(k4 + kk) * 128 + cl * 4];
                float wv[16];
                *(float4*)&wv[0] = *(const float4*)(wr);
                *(float4*)&wv[4] = *(const float4*)(wr + 32);
                *(float4*)&wv[8] = *(const float4*)(wr + 64);
                *(float4*)&wv[12] = *(const float4*)(wr + 96);
                float xs0 = (&xv0.x)[kk], xs1 = (&xv1.x)[kk];
#pragma unroll
                for (int j = 0; j < 16; ++j) {
                    acc0[j] = fmaf(xs0, wv[j], acc0[j]);
                    acc1[j] = fmaf(xs1, wv[j], acc1[j]);
                }
            }
        }
    }
    if (row0 < nrows) {
        float wd = dinv[row0];
        uint2* orow = (uint2*)&hout[(size_t)row0 * 64];
#pragma unroll
        for (int g = 0; g < 4; ++g)
            orow[cl + 8 * g] = make_uint2(packbf(acc0[4 * g] * wd, acc0[4 * g + 1] * wd),
                                          packbf(acc0[4 * g + 2] * wd, acc0[4 * g + 3] * wd));
    }
    if (row1 < nrows) {
        float wd = dinv[row1];
        uint2* orow = (uint2*)&hout[(size_t)row1 * 64];
#pragma unroll
        for (int g = 0; g < 4; ++g)
            orow[cl + 8 * g] = make_uint2(packbf(acc1[4 * g] * wd, acc1[4 * g + 1] * wd),
                                          packbf(acc1[4 * g + 2] * wd, acc1[4 * g + 3] * wd));
    }
}

// ---------------- GEMM2: [N,128]fp32 @ [128,64] -> bf16 scaled by dinv ----------------
__global__ __launch_bounds__(256) void gemm2_kernel(const float* __restrict__ hin,
                                                    const float* __restrict__ W,
                                                    const float* __restrict__ dinv,
                                                    uint32* __restrict__ hout,  // N x 32 uints
                                                    int nrows) {
    __shared__ float Wl[128 * 64];
    int tid = threadIdx.x;
    {
        const float4* Wg = (const float4*)W;
        float4* Wl4 = (float4*)Wl;
        for (int i = tid; i < 128 * 64 / 4; i += 256) Wl4[i] = Wg[i];
    }
    __syncthreads();
    int rg = tid >> 3, cl = tid & 7;
    int row0 = blockIdx.x * 64 + rg * 2;
    int row1 = row0 + 1;
    bool v0 = row0 < nrows, v1 = row1 < nrows;
    float acc0[8], acc1[8];
#pragma unroll
    for (int j = 0; j < 8; ++j) { acc0[j] = 0.f; acc1[j] = 0.f; }
    const float* hr0 = hin + (size_t)row0 * 128;
    const float* hr1 = hin + (size_t)row1 * 128;
    for (int k4 = 0; k4 < 128; k4 += 4) {
        float4 xv0 = v0 ? *(const float4*)(hr0 + k4) : make_float4(0, 0, 0, 0);
        float4 xv1 = v1 ? *(const float4*)(hr1 + k4) : make_float4(0, 0, 0, 0);
#pragma unroll
        for (int kk = 0; kk < 4; ++kk) {
            const float* wr = &Wl[(k4 + kk) * 64 + cl * 4];
            float wv[8];
            *(float4*)&wv[0] = *(const float4*)(wr);
            *(float4*)&wv[4] = *(const float4*)(wr + 32);
            float xs0 = (&xv0.x)[kk], xs1 = (&xv1.x)[kk];
#pragma unroll
            for (int j = 0; j < 8; ++j) {
                acc0[j] = fmaf(xs0, wv[j], acc0[j]);
                acc1[j] = fmaf(xs1, wv[j], acc1[j]);
            }
        }
    }
    if (v0) {
        float wd = dinv[row0];
        uint2* orow = (uint2*)&hout[(size_t)row0 * 32];
#pragma unroll
        for (int g = 0; g < 2; ++g)
            orow[cl + 8 * g] = make_uint2(packbf(acc0[4 * g] * wd, acc0[4 * g + 1] * wd),
                                          packbf(acc0[4 * g + 2] * wd, acc0[4 * g + 3] * wd));
    }
    if (v1) {
        float wd = dinv[row1];
        uint2* orow = (uint2*)&hout[(size_t)row1 * 32];
#pragma unroll
        for (int g = 0; g < 2; ++g)
            orow[cl + 8 * g] = make_uint2(packbf(acc1[4 * g] * wd, acc1[4 * g + 1] * wd),
                                          packbf(acc1[4 * g + 2] * wd, acc1[4 * g + 3] * wd));
    }
}

// ---------------- layer-1 pull aggregation (bf16 gather), fused bias+relu ----------------
// h is pre-scaled by dinv[src]; out = relu(dinv[d]*(self + sum) + b), fp32 for gemm2
__global__ __launch_bounds__(256) void agg1_kernel(const uint32* __restrict__ h,  // N x 64
                                                   const float* __restrict__ dinv,
                                                   const int* __restrict__ srt,
                                                   const int* __restrict__ rowend,
                                                   const float* __restrict__ bias,
                                                   float* __restrict__ out, int n) {
    int wid = (int)(((long)blockIdx.x * blockDim.x + threadIdx.x) >> 6);
    int lane = threadIdx.x & 63;
    if (wid >= n) return;
    int start = wid ? rowend[wid - 1] : 0;
    int end = rowend[wid];
    float a0, a1;
    {
        uint32 u = h[(size_t)wid * 64 + lane];  // self (already dinv[wid]-scaled)
        a0 = bf16lo(u); a1 = bf16hi(u);
    }
    int e = start;
    for (; e + 4 <= end; e += 4) {
        int s0 = srt[e], s1 = srt[e + 1], s2 = srt[e + 2], s3 = srt[e + 3];
        uint32 u0 = h[(size_t)s0 * 64 + lane];
        uint32 u1 = h[(size_t)s1 * 64 + lane];
        uint32 u2 = h[(size_t)s2 * 64 + lane];
        uint32 u3 = h[(size_t)s3 * 64 + lane];
        a0 += bf16lo(u0); a1 += bf16hi(u0);
        a0 += bf16lo(u1); a1 += bf16hi(u1);
        a0 += bf16lo(u2); a1 += bf16hi(u2);
        a0 += bf16lo(u3); a1 += bf16hi(u3);
    }
    for (; e < end; ++e) {
        uint32 u = h[(size_t)srt[e] * 64 + lane];
        a0 += bf16lo(u); a1 += bf16hi(u);
    }
    float wd = dinv[wid];
    float2 b = ((const float2*)bias)[lane];
    float v0 = fmaxf(fmaf(wd, a0, b.x), 0.f);
    float v1 = fmaxf(fmaf(wd, a1, b.y), 0.f);
    *(float2*)&out[(size_t)wid * 128 + lane * 2] = make_float2(v0, v1);
}

// ---------------- layer-2 pull aggregation, fused bias + log_softmax ----------------
// split wave: lanes 0-31 take even edges, 32-63 odd edges; each lane owns feature pair 2q,2q+1
__global__ __launch_bounds__(256) void agg2_ls_kernel(const uint32* __restrict__ h,  // N x 32
                                                      const float* __restrict__ dinv,
                                                      const int* __restrict__ srt,
                                                      const int* __restrict__ rowend,
                                                      const float* __restrict__ bias,
                                                      float* __restrict__ out, int n) {
    int wid = (int)(((long)blockIdx.x * blockDim.x + threadIdx.x) >> 6);
    int lane = threadIdx.x & 63;
    if (wid >= n) return;
    int start = wid ? rowend[wid - 1] : 0;
    int end = rowend[wid];
    int q = lane & 31;
    int half = lane >> 5;
    float a0 = 0.f, a1 = 0.f;
    int e = start + half;
    for (; e + 2 < end; e += 4) {
        int sa = srt[e], sb = srt[e + 2];
        uint32 ua = h[(size_t)sa * 32 + q];
        uint32 ub = h[(size_t)sb * 32 + q];
        a0 += bf16lo(ua); a1 += bf16hi(ua);
        a0 += bf16lo(ub); a1 += bf16hi(ub);
    }
    for (; e < end; e += 2) {
        uint32 u = h[(size_t)srt[e] * 32 + q];
        a0 += bf16lo(u); a1 += bf16hi(u);
    }
    // combine the two halves, then add self once
    a0 += __shfl_xor(a0, 32, WAVE);
    a1 += __shfl_xor(a1, 32, WAVE);
    {
        uint32 u = h[(size_t)wid * 32 + q];
        a0 += bf16lo(u); a1 += bf16hi(u);
    }
    float wd = dinv[wid];
    float2 b = ((const float2*)bias)[q];
    float v0 = fmaf(wd, a0, b.x);
    float v1 = fmaf(wd, a1, b.y);
    float m = fmaxf(v0, v1);
#pragma unroll
    for (int o = 16; o; o >>= 1) m = fmaxf(m, __shfl_xor(m, o, WAVE));
    float s = __expf(v0 - m) + __expf(v1 - m);
#pragma unroll
    for (int o = 16; o; o >>= 1) s += __shfl_xor(s, o, WAVE);
    float lg = __logf(s);
    if (half == 0)
        *(float2*)&out[(size_t)wid * 64 + q * 2] = make_float2(v0 - m - lg, v1 - m - lg);
}

extern "C" void kernel_launch(void* const* d_in, const int* in_sizes, int n_in,
                              void* d_out, int out_size, void* d_ws, size_t ws_size,
                              hipStream_t stream) {
    const float* x  = (const float*)d_in[0];
    const float* W1 = (const float*)d_in[1];
    const float* b1 = (const float*)d_in[2];
    const float* W2 = (const float*)d_in[3];
    const float* b2 = (const float*)d_in[4];
    const int* edge = (const int*)d_in[5];

    const int N = in_sizes[0] / 256;
    const int E = in_sizes[5] / 2;
    const int* src = edge;
    const int* dst = edge + E;

    // ws layout (4B units): cnt[N] | cursor[N] | partial[512] | dinv[N] | sorted[E]
    //                       | h1s[N*64] (bf16x2) | agg1[N*128] fp32 | h2s[N*32] (bf16x2)
    int*    cnt     = (int*)d_ws;
    int*    cursor  = cnt + N;
    int*    partial = cursor + N;
    float*  dinv    = (float*)(partial + 512);
    int*    sorted  = (int*)(dinv + N);
    uint32* h1s     = (uint32*)(sorted + E);
    float*  agg1    = (float*)(h1s + (size_t)N * 64);
    uint32* h2s     = (uint32*)(agg1 + (size_t)N * 128);
    float*  outp    = (float*)d_out;

    const int TB = 256;
    const int nScanBlocks = (N + SCAN_B - 1) / SCAN_B;

    // 1) degree + dinv
    zero_int_kernel<<<(N + TB - 1) / TB, TB, 0, stream>>>(cnt, N);
    deg_count_kernel<<<(E + TB - 1) / TB, TB, 0, stream>>>(dst, cnt, E);
    dinv_kernel<<<(N + TB - 1) / TB, TB, 0, stream>>>(cnt, dinv, N);

    // 2) CSR build (cursor becomes row_end after placement)
    scan_blocks_kernel<<<nScanBlocks, SCAN_B, 0, stream>>>(cnt, cursor, partial, N);
    scan_partials_kernel<<<1, 512, 0, stream>>>(partial, nScanBlocks);
    add_offsets_kernel<<<nScanBlocks, SCAN_B, 0, stream>>>(cursor, partial, N);
    place_kernel<<<(E + TB - 1) / TB, TB, 0, stream>>>(src, dst, cursor, sorted, E);

    // 3) h1s = bf16(dinv * (x @ W1))
    gemm1_kernel<<<(N + 63) / 64, TB, 0, stream>>>(x, W1, dinv, h1s, N);

    // 4) agg1 = relu(dinv[d]*(self+sum) + b1), fp32
    agg1_kernel<<<(N * 64 + TB - 1) / TB, TB, 0, stream>>>(h1s, dinv, sorted, cursor, b1, agg1, N);

    // 5) h2s = bf16(dinv * (agg1 @ W2))
    gemm2_kernel<<<(N + 63) / 64, TB, 0, stream>>>(agg1, W2, dinv, h2s, N);

    // 6) out = log_softmax(dinv[d]*(self+sum) + b2)
    agg2_ls_kernel<<<(N * 64 + TB - 1) / TB, TB, 0, stream>>>(h2s, dinv, sorted, cursor, b2, outp, N);
}

// Round 4
// 511.971 us; speedup vs baseline: 4.8827x; 1.6864x over previous
//
#include <hip/hip_runtime.h>
#include <hip/hip_bf16.h>

#define WAVE 64
typedef unsigned int uint32;

// ---- bf16 helpers (packed pair in a uint32: low ushort = even feature) ----
__device__ inline float bf16lo(uint32 u) { return __uint_as_float(u << 16); }
__device__ inline float bf16hi(uint32 u) { return __uint_as_float(u & 0xffff0000u); }
__device__ inline uint32 f2bf(float f) {  // round-to-nearest-even
    union { float f; uint32 u; } a; a.f = f;
    uint32 u = a.u;
    u += 0x7fffu + ((u >> 16) & 1u);
    return u >> 16;
}
__device__ inline uint32 packbf(float lo, float hi) { return f2bf(lo) | (f2bf(hi) << 16); }

// ---------------- zero small int buffer ----------------
__global__ void zero_int_kernel(int* __restrict__ p, int n) {
    int i = blockIdx.x * blockDim.x + threadIdx.x;
    if (i < n) p[i] = 0;
}

// ================= CSR build: two-pass bucket sort =================
// Bucket = dst >> 9 (512 nodes per bucket). NBUCK <= 256 (N <= 131072).
// Pass B: bin edges into per-bucket regions of `pairs`, packed src | dstLow<<17.
#define BIN_TB 1024
#define BIN_EPB 4096
__global__ __launch_bounds__(BIN_TB) void binsort_kernel(const int* __restrict__ src,
                                                         const int* __restrict__ dst,
                                                         int* __restrict__ gcnt,
                                                         uint32* __restrict__ pairs,
                                                         int E, int CAP) {
    __shared__ int hist[256];
    __shared__ int cursor[256];
    int tid = threadIdx.x;
    int base = blockIdx.x * BIN_EPB;
    if (tid < 256) hist[tid] = 0;
    __syncthreads();
    int s[4], d[4], b[4];
    bool v[4];
#pragma unroll
    for (int j = 0; j < 4; ++j) {
        int e = base + tid + j * BIN_TB;
        v[j] = e < E;
        if (v[j]) {
            s[j] = src[e];
            d[j] = dst[e];
            b[j] = d[j] >> 9;
            atomicAdd(&hist[b[j]], 1);
        }
    }
    __syncthreads();
    if (tid < 256) {
        int h = hist[tid];
        cursor[tid] = (h > 0) ? (tid * CAP + atomicAdd(&gcnt[tid], h)) : 0;
    }
    __syncthreads();
#pragma unroll
    for (int j = 0; j < 4; ++j) {
        if (v[j]) {
            int pos = atomicAdd(&cursor[b[j]], 1);
            if (pos < (b[j] + 1) * CAP)  // overflow guard (drop, ~impossible)
                pairs[pos] = (uint32)s[j] | ((uint32)(d[j] & 511) << 17);
        }
    }
}

// Pass C: per-bucket counting sort -> sorted (bucketed, CAP stride),
// plus rowstart/rowend (absolute indices into sorted) and dinv.
__global__ __launch_bounds__(512) void bucket_csr_kernel(const uint32* __restrict__ pairs,
                                                         const int* __restrict__ gcnt,
                                                         int* __restrict__ sorted,
                                                         int* __restrict__ rowstart,
                                                         int* __restrict__ rowend,
                                                         float* __restrict__ dinv,
                                                         int N, int CAP) {
    __shared__ int cnt[512];
    __shared__ int incl[512];
    __shared__ int cursor[512];
    int b = blockIdx.x;
    int tid = threadIdx.x;
    int ne = gcnt[b];
    if (ne > CAP) ne = CAP;
    const uint32* P = pairs + (size_t)b * CAP;
    cnt[tid] = 0;
    __syncthreads();
    for (int i = tid; i < ne; i += 512) atomicAdd(&cnt[P[i] >> 17], 1);
    __syncthreads();
    int v = cnt[tid];
    incl[tid] = v;
    __syncthreads();
#pragma unroll
    for (int o = 1; o < 512; o <<= 1) {
        int t = (tid >= o) ? incl[tid - o] : 0;
        __syncthreads();
        incl[tid] += t;
        __syncthreads();
    }
    int gbase = b * CAP;
    int node = b * 512 + tid;
    if (node < N) {
        rowstart[node] = gbase + incl[tid] - v;
        rowend[node] = gbase + incl[tid];
        dinv[node] = rsqrtf(1.0f + (float)v);
    }
    cursor[tid] = incl[tid] - v;
    __syncthreads();
    for (int i = tid; i < ne; i += 512) {
        uint32 p = P[i];
        int ln = p >> 17;
        int r = atomicAdd(&cursor[ln], 1);
        sorted[gbase + r] = (int)(p & 0x1FFFFu);
    }
}

// ---------------- GEMM1: [N,256]fp32 @ [256,128] -> bf16 scaled by dinv ----------------
__global__ __launch_bounds__(256) void gemm1_kernel(const float* __restrict__ x,
                                                    const float* __restrict__ W,
                                                    const float* __restrict__ dinv,
                                                    uint32* __restrict__ hout,  // N x 64 uints
                                                    int nrows) {
    __shared__ float Wl[128 * 128];
    int tid = threadIdx.x;
    int rg = tid >> 3, cl = tid & 7;
    int row0 = blockIdx.x * 64 + rg * 2;
    int row1 = row0 + 1;
    float acc0[16], acc1[16];
#pragma unroll
    for (int j = 0; j < 16; ++j) { acc0[j] = 0.f; acc1[j] = 0.f; }

    for (int kc = 0; kc < 2; ++kc) {
        __syncthreads();
        const float4* Wg = (const float4*)(W + kc * 128 * 128);
        float4* Wl4 = (float4*)Wl;
        for (int i = tid; i < 128 * 128 / 4; i += 256) Wl4[i] = Wg[i];
        __syncthreads();
        bool v0 = row0 < nrows, v1 = row1 < nrows;
        const float* xr0 = x + (size_t)row0 * 256 + kc * 128;
        const float* xr1 = x + (size_t)row1 * 256 + kc * 128;
        for (int k4 = 0; k4 < 128; k4 += 4) {
            float4 xv0 = v0 ? *(const float4*)(xr0 + k4) : make_float4(0, 0, 0, 0);
            float4 xv1 = v1 ? *(const float4*)(xr1 + k4) : make_float4(0, 0, 0, 0);
#pragma unroll
            for (int kk = 0; kk < 4; ++kk) {
                const float* wr = &Wl[(k4 + kk) * 128 + cl * 4];
                float wv[16];
                *(float4*)&wv[0] = *(const float4*)(wr);
                *(float4*)&wv[4] = *(const float4*)(wr + 32);
                *(float4*)&wv[8] = *(const float4*)(wr + 64);
                *(float4*)&wv[12] = *(const float4*)(wr + 96);
                float xs0 = (&xv0.x)[kk], xs1 = (&xv1.x)[kk];
#pragma unroll
                for (int j = 0; j < 16; ++j) {
                    acc0[j] = fmaf(xs0, wv[j], acc0[j]);
                    acc1[j] = fmaf(xs1, wv[j], acc1[j]);
                }
            }
        }
    }
    if (row0 < nrows) {
        float wd = dinv[row0];
        uint2* orow = (uint2*)&hout[(size_t)row0 * 64];
#pragma unroll
        for (int g = 0; g < 4; ++g)
            orow[cl + 8 * g] = make_uint2(packbf(acc0[4 * g] * wd, acc0[4 * g + 1] * wd),
                                          packbf(acc0[4 * g + 2] * wd, acc0[4 * g + 3] * wd));
    }
    if (row1 < nrows) {
        float wd = dinv[row1];
        uint2* orow = (uint2*)&hout[(size_t)row1 * 64];
#pragma unroll
        for (int g = 0; g < 4; ++g)
            orow[cl + 8 * g] = make_uint2(packbf(acc1[4 * g] * wd, acc1[4 * g + 1] * wd),
                                          packbf(acc1[4 * g + 2] * wd, acc1[4 * g + 3] * wd));
    }
}

// ---------------- GEMM2: [N,128]fp32 @ [128,64] -> bf16 scaled by dinv ----------------
__global__ __launch_bounds__(256) void gemm2_kernel(const float* __restrict__ hin,
                                                    const float* __restrict__ W,
                                                    const float* __restrict__ dinv,
                                                    uint32* __restrict__ hout,  // N x 32 uints
                                                    int nrows) {
    __shared__ float Wl[128 * 64];
    int tid = threadIdx.x;
    {
        const float4* Wg = (const float4*)W;
        float4* Wl4 = (float4*)Wl;
        for (int i = tid; i < 128 * 64 / 4; i += 256) Wl4[i] = Wg[i];
    }
    __syncthreads();
    int rg = tid >> 3, cl = tid & 7;
    int row0 = blockIdx.x * 64 + rg * 2;
    int row1 = row0 + 1;
    bool v0 = row0 < nrows, v1 = row1 < nrows;
    float acc0[8], acc1[8];
#pragma unroll
    for (int j = 0; j < 8; ++j) { acc0[j] = 0.f; acc1[j] = 0.f; }
    const float* hr0 = hin + (size_t)row0 * 128;
    const float* hr1 = hin + (size_t)row1 * 128;
    for (int k4 = 0; k4 < 128; k4 += 4) {
        float4 xv0 = v0 ? *(const float4*)(hr0 + k4) : make_float4(0, 0, 0, 0);
        float4 xv1 = v1 ? *(const float4*)(hr1 + k4) : make_float4(0, 0, 0, 0);
#pragma unroll
        for (int kk = 0; kk < 4; ++kk) {
            const float* wr = &Wl[(k4 + kk) * 64 + cl * 4];
            float wv[8];
            *(float4*)&wv[0] = *(const float4*)(wr);
            *(float4*)&wv[4] = *(const float4*)(wr + 32);
            float xs0 = (&xv0.x)[kk], xs1 = (&xv1.x)[kk];
#pragma unroll
            for (int j = 0; j < 8; ++j) {
                acc0[j] = fmaf(xs0, wv[j], acc0[j]);
                acc1[j] = fmaf(xs1, wv[j], acc1[j]);
            }
        }
    }
    if (v0) {
        float wd = dinv[row0];
        uint2* orow = (uint2*)&hout[(size_t)row0 * 32];
#pragma unroll
        for (int g = 0; g < 2; ++g)
            orow[cl + 8 * g] = make_uint2(packbf(acc0[4 * g] * wd, acc0[4 * g + 1] * wd),
                                          packbf(acc0[4 * g + 2] * wd, acc0[4 * g + 3] * wd));
    }
    if (v1) {
        float wd = dinv[row1];
        uint2* orow = (uint2*)&hout[(size_t)row1 * 32];
#pragma unroll
        for (int g = 0; g < 2; ++g)
            orow[cl + 8 * g] = make_uint2(packbf(acc1[4 * g] * wd, acc1[4 * g + 1] * wd),
                                          packbf(acc1[4 * g + 2] * wd, acc1[4 * g + 3] * wd));
    }
}

// ---------------- layer-1 pull aggregation (bf16 gather), fused bias+relu ----------------
__global__ __launch_bounds__(256) void agg1_kernel(const uint32* __restrict__ h,  // N x 64
                                                   const float* __restrict__ dinv,
                                                   const int* __restrict__ srt,
                                                   const int* __restrict__ rowstart,
                                                   const int* __restrict__ rowend,
                                                   const float* __restrict__ bias,
                                                   float* __restrict__ out, int n) {
    int wid = (int)(((long)blockIdx.x * blockDim.x + threadIdx.x) >> 6);
    int lane = threadIdx.x & 63;
    if (wid >= n) return;
    int start = rowstart[wid];
    int end = rowend[wid];
    float a0, a1;
    {
        uint32 u = h[(size_t)wid * 64 + lane];  // self (already dinv[wid]-scaled)
        a0 = bf16lo(u); a1 = bf16hi(u);
    }
    int e = start;
    for (; e + 4 <= end; e += 4) {
        int s0 = srt[e], s1 = srt[e + 1], s2 = srt[e + 2], s3 = srt[e + 3];
        uint32 u0 = h[(size_t)s0 * 64 + lane];
        uint32 u1 = h[(size_t)s1 * 64 + lane];
        uint32 u2 = h[(size_t)s2 * 64 + lane];
        uint32 u3 = h[(size_t)s3 * 64 + lane];
        a0 += bf16lo(u0); a1 += bf16hi(u0);
        a0 += bf16lo(u1); a1 += bf16hi(u1);
        a0 += bf16lo(u2); a1 += bf16hi(u2);
        a0 += bf16lo(u3); a1 += bf16hi(u3);
    }
    for (; e < end; ++e) {
        uint32 u = h[(size_t)srt[e] * 64 + lane];
        a0 += bf16lo(u); a1 += bf16hi(u);
    }
    float wd = dinv[wid];
    float2 b = ((const float2*)bias)[lane];
    float v0 = fmaxf(fmaf(wd, a0, b.x), 0.f);
    float v1 = fmaxf(fmaf(wd, a1, b.y), 0.f);
    *(float2*)&out[(size_t)wid * 128 + lane * 2] = make_float2(v0, v1);
}

// ---------------- layer-2 pull aggregation, fused bias + log_softmax ----------------
__global__ __launch_bounds__(256) void agg2_ls_kernel(const uint32* __restrict__ h,  // N x 32
                                                      const float* __restrict__ dinv,
                                                      const int* __restrict__ srt,
                                                      const int* __restrict__ rowstart,
                                                      const int* __restrict__ rowend,
                                                      const float* __restrict__ bias,
                                                      float* __restrict__ out, int n) {
    int wid = (int)(((long)blockIdx.x * blockDim.x + threadIdx.x) >> 6);
    int lane = threadIdx.x & 63;
    if (wid >= n) return;
    int start = rowstart[wid];
    int end = rowend[wid];
    int q = lane & 31;
    int half = lane >> 5;
    float a0 = 0.f, a1 = 0.f;
    int e = start + half;
    for (; e + 2 < end; e += 4) {
        int sa = srt[e], sb = srt[e + 2];
        uint32 ua = h[(size_t)sa * 32 + q];
        uint32 ub = h[(size_t)sb * 32 + q];
        a0 += bf16lo(ua); a1 += bf16hi(ua);
        a0 += bf16lo(ub); a1 += bf16hi(ub);
    }
    for (; e < end; e += 2) {
        uint32 u = h[(size_t)srt[e] * 32 + q];
        a0 += bf16lo(u); a1 += bf16hi(u);
    }
    a0 += __shfl_xor(a0, 32, WAVE);
    a1 += __shfl_xor(a1, 32, WAVE);
    {
        uint32 u = h[(size_t)wid * 32 + q];
        a0 += bf16lo(u); a1 += bf16hi(u);
    }
    float wd = dinv[wid];
    float2 b = ((const float2*)bias)[q];
    float v0 = fmaf(wd, a0, b.x);
    float v1 = fmaf(wd, a1, b.y);
    float m = fmaxf(v0, v1);
#pragma unroll
    for (int o = 16; o; o >>= 1) m = fmaxf(m, __shfl_xor(m, o, WAVE));
    float s = __expf(v0 - m) + __expf(v1 - m);
#pragma unroll
    for (int o = 16; o; o >>= 1) s += __shfl_xor(s, o, WAVE);
    float lg = __logf(s);
    if (half == 0)
        *(float2*)&out[(size_t)wid * 64 + q * 2] = make_float2(v0 - m - lg, v1 - m - lg);
}

extern "C" void kernel_launch(void* const* d_in, const int* in_sizes, int n_in,
                              void* d_out, int out_size, void* d_ws, size_t ws_size,
                              hipStream_t stream) {
    const float* x  = (const float*)d_in[0];
    const float* W1 = (const float*)d_in[1];
    const float* b1 = (const float*)d_in[2];
    const float* W2 = (const float*)d_in[3];
    const float* b2 = (const float*)d_in[4];
    const int* edge = (const int*)d_in[5];

    const int N = in_sizes[0] / 256;
    const int E = in_sizes[5] / 2;
    const int* src = edge;
    const int* dst = edge + E;

    const int NBUCK = (N + 511) >> 9;  // 196 for N=100000 (<=256)
    int mean = E / NBUCK;
    int CAP = mean + (int)(8.5 * __builtin_sqrt((double)mean)) + 32;
    CAP = (CAP + 63) & ~63;  // 17440 for E=3.2M

    // ws layout (4B units):
    // gcnt[256] | dinv[N] | rowstart[N] | rowend[N] | sorted[NBUCK*CAP]
    // | h1s[N*64] | h2s[N*32] | agg1[N*128] (pairs[NBUCK*CAP] aliases agg1 region)
    int*    gcnt     = (int*)d_ws;
    float*  dinv     = (float*)(gcnt + 256);
    int*    rowstart = (int*)(dinv + N);
    int*    rowend   = rowstart + N;
    int*    sorted   = rowend + N;
    uint32* h1s      = (uint32*)(sorted + (size_t)NBUCK * CAP);
    uint32* h2s      = h1s + (size_t)N * 64;
    float*  agg1     = (float*)(h2s + (size_t)N * 32);
    uint32* pairs    = (uint32*)agg1;  // dead after bucket_csr; agg1 written later
    float*  outp     = (float*)d_out;

    const int TB = 256;

    // 1) CSR build via two-pass bucket sort (also produces dinv)
    zero_int_kernel<<<1, 256, 0, stream>>>(gcnt, 256);
    binsort_kernel<<<(E + BIN_EPB - 1) / BIN_EPB, BIN_TB, 0, stream>>>(src, dst, gcnt, pairs, E, CAP);
    bucket_csr_kernel<<<NBUCK, 512, 0, stream>>>(pairs, gcnt, sorted, rowstart, rowend, dinv, N, CAP);

    // 2) h1s = bf16(dinv * (x @ W1))
    gemm1_kernel<<<(N + 63) / 64, TB, 0, stream>>>(x, W1, dinv, h1s, N);

    // 3) agg1 = relu(dinv[d]*(self+sum) + b1), fp32
    agg1_kernel<<<(N * 64 + TB - 1) / TB, TB, 0, stream>>>(h1s, dinv, sorted, rowstart, rowend, b1, agg1, N);

    // 4) h2s = bf16(dinv * (agg1 @ W2))
    gemm2_kernel<<<(N + 63) / 64, TB, 0, stream>>>(agg1, W2, dinv, h2s, N);

    // 5) out = log_softmax(dinv[d]*(self+sum) + b2)
    agg2_ls_kernel<<<(N * 64 + TB - 1) / TB, TB, 0, stream>>>(h2s, dinv, sorted, rowstart, rowend, b2, outp, N);
}

// Round 5
// 339.669 us; speedup vs baseline: 7.3596x; 1.5073x over previous
//
#include <hip/hip_runtime.h>
#include <hip/hip_bf16.h>

#define WAVE 64
typedef unsigned int uint32;
typedef __attribute__((ext_vector_type(8))) short bf16x8;
typedef __attribute__((ext_vector_type(4))) float f32x4;

// ---- bf16 helpers ----
__device__ inline float bf16lo(uint32 u) { return __uint_as_float(u << 16); }
__device__ inline float bf16hi(uint32 u) { return __uint_as_float(u & 0xffff0000u); }
__device__ inline uint32 f2bf(float f) {  // round-to-nearest-even, bits in low 16
    union { float f; uint32 u; } a; a.f = f;
    uint32 u = a.u;
    u += 0x7fffu + ((u >> 16) & 1u);
    return u >> 16;
}
__device__ inline uint32 packbf(float lo, float hi) { return f2bf(lo) | (f2bf(hi) << 16); }
__device__ inline short f2bfs(float f) { return (short)f2bf(f); }

// ---------------- zero small int buffer ----------------
__global__ void zero_int_kernel(int* __restrict__ p, int n) {
    int i = blockIdx.x * blockDim.x + threadIdx.x;
    if (i < n) p[i] = 0;
}

// ---------------- W1/W2 -> fragment-ordered bf16 ----------------
// w1f: chunks (kc*8+c)*64+l, chunk = bf16x8 of W1[k][n], k=kc*32+(l>>4)*8+j, n=c*16+(l&15)
// w2f: chunks (kc*4+c)*64+l of W2 (128x64)
__global__ void convert_w_kernel(const float* __restrict__ W1, const float* __restrict__ W2,
                                 uint32* __restrict__ w1f, uint32* __restrict__ w2f) {
    int tid = blockIdx.x * blockDim.x + threadIdx.x;  // 0..20479
    if (tid < 16384) {
        int w = tid & 3, l = (tid >> 2) & 63, c = (tid >> 8) & 7, kc = tid >> 11;
        int q = l & 15, g = l >> 4;
        int k0 = kc * 32 + g * 8 + 2 * w;
        int n = c * 16 + q;
        w1f[tid] = packbf(W1[k0 * 128 + n], W1[(k0 + 1) * 128 + n]);
    } else if (tid < 16384 + 4096) {
        int t = tid - 16384;
        int w = t & 3, l = (t >> 2) & 63, c = (t >> 8) & 3, kc = t >> 10;
        int q = l & 15, g = l >> 4;
        int k0 = kc * 32 + g * 8 + 2 * w;
        int n = c * 16 + q;
        w2f[t] = packbf(W2[k0 * 64 + n], W2[(k0 + 1) * 64 + n]);
    }
}

// ================= CSR build: two-pass bucket sort =================
#define BIN_TB 1024
#define BIN_EPB 4096
__global__ __launch_bounds__(BIN_TB) void binsort_kernel(const int* __restrict__ src,
                                                         const int* __restrict__ dst,
                                                         int* __restrict__ gcnt,
                                                         uint32* __restrict__ pairs,
                                                         int E, int CAP) {
    __shared__ int hist[256];
    __shared__ int cursor[256];
    int tid = threadIdx.x;
    int base = blockIdx.x * BIN_EPB;
    if (tid < 256) hist[tid] = 0;
    __syncthreads();
    int s[4], d[4], b[4];
    bool v[4];
#pragma unroll
    for (int j = 0; j < 4; ++j) {
        int e = base + tid + j * BIN_TB;
        v[j] = e < E;
        if (v[j]) {
            s[j] = src[e];
            d[j] = dst[e];
            b[j] = d[j] >> 9;
            atomicAdd(&hist[b[j]], 1);
        }
    }
    __syncthreads();
    if (tid < 256) {
        int h = hist[tid];
        cursor[tid] = (h > 0) ? (tid * CAP + atomicAdd(&gcnt[tid], h)) : 0;
    }
    __syncthreads();
#pragma unroll
    for (int j = 0; j < 4; ++j) {
        if (v[j]) {
            int pos = atomicAdd(&cursor[b[j]], 1);
            if (pos < (b[j] + 1) * CAP)
                pairs[pos] = (uint32)s[j] | ((uint32)(d[j] & 511) << 17);
        }
    }
}

__global__ __launch_bounds__(512) void bucket_csr_kernel(const uint32* __restrict__ pairs,
                                                         const int* __restrict__ gcnt,
                                                         int* __restrict__ sorted,
                                                         int* __restrict__ rowstart,
                                                         int* __restrict__ rowend,
                                                         float* __restrict__ dinv,
                                                         int N, int CAP) {
    __shared__ int cnt[512];
    __shared__ int incl[512];
    __shared__ int cursor[512];
    int b = blockIdx.x;
    int tid = threadIdx.x;
    int ne = gcnt[b];
    if (ne > CAP) ne = CAP;
    const uint32* P = pairs + (size_t)b * CAP;
    cnt[tid] = 0;
    __syncthreads();
    for (int i = tid; i < ne; i += 512) atomicAdd(&cnt[P[i] >> 17], 1);
    __syncthreads();
    int v = cnt[tid];
    incl[tid] = v;
    __syncthreads();
#pragma unroll
    for (int o = 1; o < 512; o <<= 1) {
        int t = (tid >= o) ? incl[tid - o] : 0;
        __syncthreads();
        incl[tid] += t;
        __syncthreads();
    }
    int gbase = b * CAP;
    int node = b * 512 + tid;
    if (node < N) {
        rowstart[node] = gbase + incl[tid] - v;
        rowend[node] = gbase + incl[tid];
        dinv[node] = rsqrtf(1.0f + (float)v);
    }
    cursor[tid] = incl[tid] - v;
    __syncthreads();
    for (int i = tid; i < ne; i += 512) {
        uint32 p = P[i];
        int ln = p >> 17;
        int r = atomicAdd(&cursor[ln], 1);
        sorted[gbase + r] = (int)(p & 0x1FFFFu);
    }
}

// ---------------- GEMM1 (MFMA): [N,256]fp32 @ W1F -> h1s bf16 pairs (f, f+64) ----------------
// block = 128 rows (4 waves x 32), K=256 in 8 chunks, out cols 128 = 8 tiles
__global__ __launch_bounds__(256) void gemm1_mfma(const float* __restrict__ x,
                                                  const uint32* __restrict__ w1f,
                                                  const float* __restrict__ dinv,
                                                  uint32* __restrict__ hout,  // N x 64
                                                  int N) {
    const bf16x8* Bp = (const bf16x8*)w1f;
    int l = threadIdx.x & 63, w = threadIdx.x >> 6;
    int q = l & 15, g = l >> 4;
    int R = blockIdx.x * 128 + w * 32;
    f32x4 acc[2][8];
#pragma unroll
    for (int rt = 0; rt < 2; ++rt)
#pragma unroll
        for (int c = 0; c < 8; ++c) acc[rt][c] = (f32x4){0.f, 0.f, 0.f, 0.f};

#pragma unroll
    for (int kc = 0; kc < 8; ++kc) {
        bf16x8 b[8];
#pragma unroll
        for (int c = 0; c < 8; ++c) b[c] = Bp[(kc * 8 + c) * 64 + l];
#pragma unroll
        for (int rt = 0; rt < 2; ++rt) {
            int row = R + rt * 16 + q;
            row = row < N ? row : N - 1;
            const float* xr = x + (size_t)row * 256 + kc * 32 + g * 8;
            float4 xa = *(const float4*)xr;
            float4 xb = *(const float4*)(xr + 4);
            bf16x8 a;
            a[0] = f2bfs(xa.x); a[1] = f2bfs(xa.y); a[2] = f2bfs(xa.z); a[3] = f2bfs(xa.w);
            a[4] = f2bfs(xb.x); a[5] = f2bfs(xb.y); a[6] = f2bfs(xb.z); a[7] = f2bfs(xb.w);
#pragma unroll
            for (int c = 0; c < 8; ++c)
                acc[rt][c] = __builtin_amdgcn_mfma_f32_16x16x32_bf16(a, b[c], acc[rt][c], 0, 0, 0);
        }
    }
#pragma unroll
    for (int rt = 0; rt < 2; ++rt)
#pragma unroll
        for (int r = 0; r < 4; ++r) {
            int grow = R + rt * 16 + 4 * g + r;
            if (grow < N) {
                float wd = dinv[grow];
                uint32* orow = hout + (size_t)grow * 64;
#pragma unroll
                for (int c = 0; c < 4; ++c)
                    orow[c * 16 + q] = packbf(acc[rt][c][r] * wd, acc[rt][c + 4][r] * wd);
            }
        }
}

// ---------------- GEMM2 (MFMA): [N,128]fp32 @ W2F -> h2s bf16 pairs (f, f+32) ----------------
__global__ __launch_bounds__(256) void gemm2_mfma(const float* __restrict__ hin,
                                                  const uint32* __restrict__ w2f,
                                                  const float* __restrict__ dinv,
                                                  uint32* __restrict__ hout,  // N x 32
                                                  int N) {
    const bf16x8* Bp = (const bf16x8*)w2f;
    int l = threadIdx.x & 63, w = threadIdx.x >> 6;
    int q = l & 15, g = l >> 4;
    int R = blockIdx.x * 128 + w * 32;
    f32x4 acc[2][4];
#pragma unroll
    for (int rt = 0; rt < 2; ++rt)
#pragma unroll
        for (int c = 0; c < 4; ++c) acc[rt][c] = (f32x4){0.f, 0.f, 0.f, 0.f};

#pragma unroll
    for (int kc = 0; kc < 4; ++kc) {
        bf16x8 b[4];
#pragma unroll
        for (int c = 0; c < 4; ++c) b[c] = Bp[(kc * 4 + c) * 64 + l];
#pragma unroll
        for (int rt = 0; rt < 2; ++rt) {
            int row = R + rt * 16 + q;
            row = row < N ? row : N - 1;
            const float* xr = hin + (size_t)row * 128 + kc * 32 + g * 8;
            float4 xa = *(const float4*)xr;
            float4 xb = *(const float4*)(xr + 4);
            bf16x8 a;
            a[0] = f2bfs(xa.x); a[1] = f2bfs(xa.y); a[2] = f2bfs(xa.z); a[3] = f2bfs(xa.w);
            a[4] = f2bfs(xb.x); a[5] = f2bfs(xb.y); a[6] = f2bfs(xb.z); a[7] = f2bfs(xb.w);
#pragma unroll
            for (int c = 0; c < 4; ++c)
                acc[rt][c] = __builtin_amdgcn_mfma_f32_16x16x32_bf16(a, b[c], acc[rt][c], 0, 0, 0);
        }
    }
#pragma unroll
    for (int rt = 0; rt < 2; ++rt)
#pragma unroll
        for (int r = 0; r < 4; ++r) {
            int grow = R + rt * 16 + 4 * g + r;
            if (grow < N) {
                float wd = dinv[grow];
                uint32* orow = hout + (size_t)grow * 32;
#pragma unroll
                for (int c = 0; c < 2; ++c)
                    orow[c * 16 + q] = packbf(acc[rt][c][r] * wd, acc[rt][c + 2][r] * wd);
            }
        }
}

// ---------------- layer-1 pull aggregation: u32 f = features (f, f+64) ----------------
__global__ __launch_bounds__(256) void agg1_kernel(const uint32* __restrict__ h,  // N x 64
                                                   const float* __restrict__ dinv,
                                                   const int* __restrict__ srt,
                                                   const int* __restrict__ rowstart,
                                                   const int* __restrict__ rowend,
                                                   const float* __restrict__ bias,
                                                   float* __restrict__ out, int n) {
    int wid = (int)(((long)blockIdx.x * blockDim.x + threadIdx.x) >> 6);
    int lane = threadIdx.x & 63;
    if (wid >= n) return;
    int start = rowstart[wid];
    int end = rowend[wid];
    float a0, a1;
    {
        uint32 u = h[(size_t)wid * 64 + lane];  // self (already dinv-scaled)
        a0 = bf16lo(u); a1 = bf16hi(u);
    }
    int e = start;
    for (; e + 4 <= end; e += 4) {
        int s0 = srt[e], s1 = srt[e + 1], s2 = srt[e + 2], s3 = srt[e + 3];
        uint32 u0 = h[(size_t)s0 * 64 + lane];
        uint32 u1 = h[(size_t)s1 * 64 + lane];
        uint32 u2 = h[(size_t)s2 * 64 + lane];
        uint32 u3 = h[(size_t)s3 * 64 + lane];
        a0 += bf16lo(u0); a1 += bf16hi(u0);
        a0 += bf16lo(u1); a1 += bf16hi(u1);
        a0 += bf16lo(u2); a1 += bf16hi(u2);
        a0 += bf16lo(u3); a1 += bf16hi(u3);
    }
    for (; e < end; ++e) {
        uint32 u = h[(size_t)srt[e] * 64 + lane];
        a0 += bf16lo(u); a1 += bf16hi(u);
    }
    float wd = dinv[wid];
    float v0 = fmaxf(fmaf(wd, a0, bias[lane]), 0.f);
    float v1 = fmaxf(fmaf(wd, a1, bias[lane + 64]), 0.f);
    out[(size_t)wid * 128 + lane] = v0;        // natural feature order
    out[(size_t)wid * 128 + lane + 64] = v1;
}

// ---------------- layer-2 pull aggregation + log_softmax: u32 q = (q, q+32) ----------------
__global__ __launch_bounds__(256) void agg2_ls_kernel(const uint32* __restrict__ h,  // N x 32
                                                      const float* __restrict__ dinv,
                                                      const int* __restrict__ srt,
                                                      const int* __restrict__ rowstart,
                                                      const int* __restrict__ rowend,
                                                      const float* __restrict__ bias,
                                                      float* __restrict__ out, int n) {
    int wid = (int)(((long)blockIdx.x * blockDim.x + threadIdx.x) >> 6);
    int lane = threadIdx.x & 63;
    if (wid >= n) return;
    int start = rowstart[wid];
    int end = rowend[wid];
    int q = lane & 31;
    int half = lane >> 5;
    float a0 = 0.f, a1 = 0.f;
    int e = start + half;
    for (; e + 2 < end; e += 4) {
        int sa = srt[e], sb = srt[e + 2];
        uint32 ua = h[(size_t)sa * 32 + q];
        uint32 ub = h[(size_t)sb * 32 + q];
        a0 += bf16lo(ua); a1 += bf16hi(ua);
        a0 += bf16lo(ub); a1 += bf16hi(ub);
    }
    for (; e < end; e += 2) {
        uint32 u = h[(size_t)srt[e] * 32 + q];
        a0 += bf16lo(u); a1 += bf16hi(u);
    }
    a0 += __shfl_xor(a0, 32, WAVE);
    a1 += __shfl_xor(a1, 32, WAVE);
    {
        uint32 u = h[(size_t)wid * 32 + q];
        a0 += bf16lo(u); a1 += bf16hi(u);
    }
    float wd = dinv[wid];
    float v0 = fmaf(wd, a0, bias[q]);
    float v1 = fmaf(wd, a1, bias[q + 32]);
    float m = fmaxf(v0, v1);
#pragma unroll
    for (int o = 16; o; o >>= 1) m = fmaxf(m, __shfl_xor(m, o, WAVE));
    float s = __expf(v0 - m) + __expf(v1 - m);
#pragma unroll
    for (int o = 16; o; o >>= 1) s += __shfl_xor(s, o, WAVE);
    float lg = __logf(s);
    if (half == 0) {
        out[(size_t)wid * 64 + q] = v0 - m - lg;
        out[(size_t)wid * 64 + q + 32] = v1 - m - lg;
    }
}

extern "C" void kernel_launch(void* const* d_in, const int* in_sizes, int n_in,
                              void* d_out, int out_size, void* d_ws, size_t ws_size,
                              hipStream_t stream) {
    const float* x  = (const float*)d_in[0];
    const float* W1 = (const float*)d_in[1];
    const float* b1 = (const float*)d_in[2];
    const float* W2 = (const float*)d_in[3];
    const float* b2 = (const float*)d_in[4];
    const int* edge = (const int*)d_in[5];

    const int N = in_sizes[0] / 256;
    const int E = in_sizes[5] / 2;
    const int* src = edge;
    const int* dst = edge + E;

    const int NBUCK = (N + 511) >> 9;  // <=256
    int mean = E / NBUCK;
    int CAP = mean + (int)(8.5 * __builtin_sqrt((double)mean)) + 32;
    CAP = (CAP + 63) & ~63;

    // ws layout (4B units): gcnt[256] | w1f[16384] | w2f[4096] | dinv[N] | rowstart[N]
    //   | rowend[N] | sorted[NBUCK*CAP] | h1s[N*64] | h2s[N*32] | agg1[N*128] (pairs alias)
    int*    gcnt     = (int*)d_ws;
    uint32* w1f      = (uint32*)(gcnt + 256);
    uint32* w2f      = w1f + 16384;
    float*  dinv     = (float*)(w2f + 4096);
    int*    rowstart = (int*)(dinv + N);
    int*    rowend   = rowstart + N;
    int*    sorted   = rowend + N;
    uint32* h1s      = (uint32*)(sorted + (size_t)NBUCK * CAP);
    uint32* h2s      = h1s + (size_t)N * 64;
    float*  agg1     = (float*)(h2s + (size_t)N * 32);
    uint32* pairs    = (uint32*)agg1;  // dead before agg1 is written
    float*  outp     = (float*)d_out;

    const int TB = 256;

    // 0) weight conversion to fragment-ordered bf16
    convert_w_kernel<<<80, TB, 0, stream>>>(W1, W2, w1f, w2f);

    // 1) CSR build via two-pass bucket sort (also produces dinv)
    zero_int_kernel<<<1, 256, 0, stream>>>(gcnt, 256);
    binsort_kernel<<<(E + BIN_EPB - 1) / BIN_EPB, BIN_TB, 0, stream>>>(src, dst, gcnt, pairs, E, CAP);
    bucket_csr_kernel<<<NBUCK, 512, 0, stream>>>(pairs, gcnt, sorted, rowstart, rowend, dinv, N, CAP);

    // 2) h1s = bf16(dinv * (x @ W1))  [MFMA]
    gemm1_mfma<<<(N + 127) / 128, TB, 0, stream>>>(x, w1f, dinv, h1s, N);

    // 3) agg1 = relu(dinv[d]*(self+sum) + b1), fp32 natural order
    agg1_kernel<<<(N * 64 + TB - 1) / TB, TB, 0, stream>>>(h1s, dinv, sorted, rowstart, rowend, b1, agg1, N);

    // 4) h2s = bf16(dinv * (agg1 @ W2))  [MFMA]
    gemm2_mfma<<<(N + 127) / 128, TB, 0, stream>>>(agg1, w2f, dinv, h2s, N);

    // 5) out = log_softmax(dinv[d]*(self+sum) + b2)
    agg2_ls_kernel<<<(N * 64 + TB - 1) / TB, TB, 0, stream>>>(h2s, dinv, sorted, rowstart, rowend, b2, outp, N);
}

// Round 6
// 300.979 us; speedup vs baseline: 8.3056x; 1.1285x over previous
//
#include <hip/hip_runtime.h>
#include <hip/hip_bf16.h>

#define WAVE 64
typedef unsigned int uint32;
typedef __attribute__((ext_vector_type(8))) short bf16x8;
typedef __attribute__((ext_vector_type(4))) float f32x4;

// ---- bf16 helpers ----
__device__ inline float bf16lo(uint32 u) { return __uint_as_float(u << 16); }
__device__ inline float bf16hi(uint32 u) { return __uint_as_float(u & 0xffff0000u); }
__device__ inline uint32 f2bf(float f) {  // round-to-nearest-even, bits in low 16
    union { float f; uint32 u; } a; a.f = f;
    uint32 u = a.u;
    u += 0x7fffu + ((u >> 16) & 1u);
    return u >> 16;
}
__device__ inline uint32 packbf(float lo, float hi) { return f2bf(lo) | (f2bf(hi) << 16); }
__device__ inline short f2bfs(float f) { return (short)f2bf(f); }

// ---------------- W1/W2 -> fragment-ordered bf16 (+ gcnt zeroing) ----------------
__global__ void convert_w_kernel(const float* __restrict__ W1, const float* __restrict__ W2,
                                 uint32* __restrict__ w1f, uint32* __restrict__ w2f,
                                 int* __restrict__ gcnt) {
    int tid = blockIdx.x * blockDim.x + threadIdx.x;  // 0..20479
    if (tid < 256) gcnt[tid] = 0;
    if (tid < 16384) {
        int w = tid & 3, l = (tid >> 2) & 63, c = (tid >> 8) & 7, kc = tid >> 11;
        int q = l & 15, g = l >> 4;
        int k0 = kc * 32 + g * 8 + 2 * w;
        int n = c * 16 + q;
        w1f[tid] = packbf(W1[k0 * 128 + n], W1[(k0 + 1) * 128 + n]);
    } else if (tid < 16384 + 4096) {
        int t = tid - 16384;
        int w = t & 3, l = (t >> 2) & 63, c = (t >> 8) & 3, kc = t >> 10;
        int q = l & 15, g = l >> 4;
        int k0 = kc * 32 + g * 8 + 2 * w;
        int n = c * 16 + q;
        w2f[t] = packbf(W2[k0 * 64 + n], W2[(k0 + 1) * 64 + n]);
    }
}

// ================= CSR build: two-pass bucket sort =================
#define BIN_TB 1024
#define BIN_EPB 4096
__global__ __launch_bounds__(BIN_TB) void binsort_kernel(const int* __restrict__ src,
                                                         const int* __restrict__ dst,
                                                         int* __restrict__ gcnt,
                                                         uint32* __restrict__ pairs,
                                                         int E, int CAP) {
    __shared__ int hist[256];
    __shared__ int cursor[256];
    int tid = threadIdx.x;
    int base = blockIdx.x * BIN_EPB;
    if (tid < 256) hist[tid] = 0;
    __syncthreads();
    int s[4], d[4], b[4];
    bool v[4];
#pragma unroll
    for (int j = 0; j < 4; ++j) {
        int e = base + tid + j * BIN_TB;
        v[j] = e < E;
        if (v[j]) {
            s[j] = src[e];
            d[j] = dst[e];
            b[j] = d[j] >> 9;
            atomicAdd(&hist[b[j]], 1);
        }
    }
    __syncthreads();
    if (tid < 256) {
        int h = hist[tid];
        cursor[tid] = (h > 0) ? (tid * CAP + atomicAdd(&gcnt[tid], h)) : 0;
    }
    __syncthreads();
#pragma unroll
    for (int j = 0; j < 4; ++j) {
        if (v[j]) {
            int pos = atomicAdd(&cursor[b[j]], 1);
            if (pos < (b[j] + 1) * CAP)
                pairs[pos] = (uint32)s[j] | ((uint32)(d[j] & 511) << 17);
        }
    }
}

__global__ __launch_bounds__(512) void bucket_csr_kernel(const uint32* __restrict__ pairs,
                                                         const int* __restrict__ gcnt,
                                                         int* __restrict__ sorted,
                                                         int* __restrict__ rowstart,
                                                         int* __restrict__ rowend,
                                                         float* __restrict__ dinv,
                                                         int N, int CAP) {
    __shared__ int cnt[512];
    __shared__ int incl[512];
    __shared__ int cursor[512];
    int b = blockIdx.x;
    int tid = threadIdx.x;
    int ne = gcnt[b];
    if (ne > CAP) ne = CAP;
    const uint32* P = pairs + (size_t)b * CAP;
    cnt[tid] = 0;
    __syncthreads();
    for (int i = tid; i < ne; i += 512) atomicAdd(&cnt[P[i] >> 17], 1);
    __syncthreads();
    int v = cnt[tid];
    incl[tid] = v;
    __syncthreads();
#pragma unroll
    for (int o = 1; o < 512; o <<= 1) {
        int t = (tid >= o) ? incl[tid - o] : 0;
        __syncthreads();
        incl[tid] += t;
        __syncthreads();
    }
    int gbase = b * CAP;
    int node = b * 512 + tid;
    if (node < N) {
        rowstart[node] = gbase + incl[tid] - v;
        rowend[node] = gbase + incl[tid];
        dinv[node] = rsqrtf(1.0f + (float)v);
    }
    cursor[tid] = incl[tid] - v;
    __syncthreads();
    for (int i = tid; i < ne; i += 512) {
        uint32 p = P[i];
        int ln = p >> 17;
        int r = atomicAdd(&cursor[ln], 1);
        sorted[gbase + r] = (int)(p & 0x1FFFFu);
    }
}

// ---------------- GEMM1 (MFMA): [N,256]fp32 @ W1F -> h1s bf16 pairs (f, f+64) ----------------
__global__ __launch_bounds__(256) void gemm1_mfma(const float* __restrict__ x,
                                                  const uint32* __restrict__ w1f,
                                                  const float* __restrict__ dinv,
                                                  uint32* __restrict__ hout,  // N x 64
                                                  int N) {
    const bf16x8* Bp = (const bf16x8*)w1f;
    int l = threadIdx.x & 63, w = threadIdx.x >> 6;
    int q = l & 15, g = l >> 4;
    int R = blockIdx.x * 128 + w * 32;
    f32x4 acc[2][8];
#pragma unroll
    for (int rt = 0; rt < 2; ++rt)
#pragma unroll
        for (int c = 0; c < 8; ++c) acc[rt][c] = (f32x4){0.f, 0.f, 0.f, 0.f};

#pragma unroll
    for (int kc = 0; kc < 8; ++kc) {
        bf16x8 b[8];
#pragma unroll
        for (int c = 0; c < 8; ++c) b[c] = Bp[(kc * 8 + c) * 64 + l];
#pragma unroll
        for (int rt = 0; rt < 2; ++rt) {
            int row = R + rt * 16 + q;
            row = row < N ? row : N - 1;
            const float* xr = x + (size_t)row * 256 + kc * 32 + g * 8;
            float4 xa = *(const float4*)xr;
            float4 xb = *(const float4*)(xr + 4);
            bf16x8 a;
            a[0] = f2bfs(xa.x); a[1] = f2bfs(xa.y); a[2] = f2bfs(xa.z); a[3] = f2bfs(xa.w);
            a[4] = f2bfs(xb.x); a[5] = f2bfs(xb.y); a[6] = f2bfs(xb.z); a[7] = f2bfs(xb.w);
#pragma unroll
            for (int c = 0; c < 8; ++c)
                acc[rt][c] = __builtin_amdgcn_mfma_f32_16x16x32_bf16(a, b[c], acc[rt][c], 0, 0, 0);
        }
    }
#pragma unroll
    for (int rt = 0; rt < 2; ++rt)
#pragma unroll
        for (int r = 0; r < 4; ++r) {
            int grow = R + rt * 16 + 4 * g + r;
            if (grow < N) {
                float wd = dinv[grow];
                uint32* orow = hout + (size_t)grow * 64;
#pragma unroll
                for (int c = 0; c < 4; ++c)
                    orow[c * 16 + q] = packbf(acc[rt][c][r] * wd, acc[rt][c + 4][r] * wd);
            }
        }
}

// ---------------- layer-1 pull aggregation: uint2 loads, 2 edges per wave-instr ----------------
// h rows: 32 uint2; uint2 j = features (2j, 2j+64, 2j+1, 2j+65).
// Output: bf16 natural order (uint32 j = features 2j,2j+1), relu'd, ready as gemm2 A.
__global__ __launch_bounds__(256) void agg1_kernel(const uint32* __restrict__ h,  // N x 64
                                                   const float* __restrict__ dinv,
                                                   const int* __restrict__ srt,
                                                   const int* __restrict__ rowstart,
                                                   const int* __restrict__ rowend,
                                                   const float* __restrict__ bias,
                                                   uint32* __restrict__ out,  // N x 64 bf16-pairs
                                                   int n) {
    int wid = (int)(((long)blockIdx.x * blockDim.x + threadIdx.x) >> 6);
    int lane = threadIdx.x & 63;
    if (wid >= n) return;
    const uint2* h2 = (const uint2*)h;
    int q = lane & 31;
    int half = lane >> 5;
    int start = rowstart[wid];
    int end = rowend[wid];
    float a0 = 0.f, a1 = 0.f, a2 = 0.f, a3 = 0.f;
    if (half == 0) {  // self (already dinv-scaled)
        uint2 us = h2[(size_t)wid * 32 + q];
        a0 = bf16lo(us.x); a1 = bf16hi(us.x);
        a2 = bf16lo(us.y); a3 = bf16hi(us.y);
    }
    int e = start + half;
    for (; e + 2 < end; e += 4) {
        int sa = srt[e], sb = srt[e + 2];
        uint2 ua = h2[(size_t)sa * 32 + q];
        uint2 ub = h2[(size_t)sb * 32 + q];
        a0 += bf16lo(ua.x); a1 += bf16hi(ua.x);
        a2 += bf16lo(ua.y); a3 += bf16hi(ua.y);
        a0 += bf16lo(ub.x); a1 += bf16hi(ub.x);
        a2 += bf16lo(ub.y); a3 += bf16hi(ub.y);
    }
    for (; e < end; e += 2) {
        uint2 u = h2[(size_t)srt[e] * 32 + q];
        a0 += bf16lo(u.x); a1 += bf16hi(u.x);
        a2 += bf16lo(u.y); a3 += bf16hi(u.y);
    }
    a0 += __shfl_xor(a0, 32, WAVE);
    a1 += __shfl_xor(a1, 32, WAVE);
    a2 += __shfl_xor(a2, 32, WAVE);
    a3 += __shfl_xor(a3, 32, WAVE);
    float wd = dinv[wid];
    float2 blo = ((const float2*)bias)[q];        // b[2q], b[2q+1]
    float2 bhi = ((const float2*)bias)[q + 32];   // b[2q+64], b[2q+65]
    float v0 = fmaxf(fmaf(wd, a0, blo.x), 0.f);   // feat 2q
    float v2 = fmaxf(fmaf(wd, a2, blo.y), 0.f);   // feat 2q+1
    float v1 = fmaxf(fmaf(wd, a1, bhi.x), 0.f);   // feat 2q+64
    float v3 = fmaxf(fmaf(wd, a3, bhi.y), 0.f);   // feat 2q+65
    uint32* orow = out + (size_t)wid * 64;
    if (half == 0) orow[q] = packbf(v0, v2);
    else           orow[q + 32] = packbf(v1, v3);
}

// ---------------- GEMM2 (MFMA): [N,128]bf16 @ W2F -> h2s bf16 pairs (f, f+32) ----------------
__global__ __launch_bounds__(256) void gemm2_mfma(const uint32* __restrict__ hin,  // N x 64 bf16-pairs
                                                  const uint32* __restrict__ w2f,
                                                  const float* __restrict__ dinv,
                                                  uint32* __restrict__ hout,  // N x 32
                                                  int N) {
    const bf16x8* Bp = (const bf16x8*)w2f;
    const short* hs = (const short*)hin;
    int l = threadIdx.x & 63, w = threadIdx.x >> 6;
    int q = l & 15, g = l >> 4;
    int R = blockIdx.x * 128 + w * 32;
    f32x4 acc[2][4];
#pragma unroll
    for (int rt = 0; rt < 2; ++rt)
#pragma unroll
        for (int c = 0; c < 4; ++c) acc[rt][c] = (f32x4){0.f, 0.f, 0.f, 0.f};

#pragma unroll
    for (int kc = 0; kc < 4; ++kc) {
        bf16x8 b[4];
#pragma unroll
        for (int c = 0; c < 4; ++c) b[c] = Bp[(kc * 4 + c) * 64 + l];
#pragma unroll
        for (int rt = 0; rt < 2; ++rt) {
            int row = R + rt * 16 + q;
            row = row < N ? row : N - 1;
            bf16x8 a = *(const bf16x8*)(hs + (size_t)row * 128 + kc * 32 + g * 8);
#pragma unroll
            for (int c = 0; c < 4; ++c)
                acc[rt][c] = __builtin_amdgcn_mfma_f32_16x16x32_bf16(a, b[c], acc[rt][c], 0, 0, 0);
        }
    }
#pragma unroll
    for (int rt = 0; rt < 2; ++rt)
#pragma unroll
        for (int r = 0; r < 4; ++r) {
            int grow = R + rt * 16 + 4 * g + r;
            if (grow < N) {
                float wd = dinv[grow];
                uint32* orow = hout + (size_t)grow * 32;
#pragma unroll
                for (int c = 0; c < 2; ++c)
                    orow[c * 16 + q] = packbf(acc[rt][c][r] * wd, acc[rt][c + 2][r] * wd);
            }
        }
}

// ---------------- layer-2 pull aggregation + log_softmax: uint2 loads, 4 edges/instr ----------------
// h rows: 16 uint2; uint2 j = features (2j, 2j+32, 2j+1, 2j+33). Quads of 16 lanes take edge strides.
__global__ __launch_bounds__(256) void agg2_ls_kernel(const uint32* __restrict__ h,  // N x 32
                                                      const float* __restrict__ dinv,
                                                      const int* __restrict__ srt,
                                                      const int* __restrict__ rowstart,
                                                      const int* __restrict__ rowend,
                                                      const float* __restrict__ bias,
                                                      float* __restrict__ out, int n) {
    int wid = (int)(((long)blockIdx.x * blockDim.x + threadIdx.x) >> 6);
    int lane = threadIdx.x & 63;
    if (wid >= n) return;
    const uint2* h2 = (const uint2*)h;
    int q = lane & 15;
    int quad = lane >> 4;
    int start = rowstart[wid];
    int end = rowend[wid];
    float a0 = 0.f, a1 = 0.f, a2 = 0.f, a3 = 0.f;
    if (quad == 0) {  // self
        uint2 us = h2[(size_t)wid * 16 + q];
        a0 = bf16lo(us.x); a1 = bf16hi(us.x);
        a2 = bf16lo(us.y); a3 = bf16hi(us.y);
    }
    int e = start + quad;
    for (; e + 4 < end; e += 8) {
        int sa = srt[e], sb = srt[e + 4];
        uint2 ua = h2[(size_t)sa * 16 + q];
        uint2 ub = h2[(size_t)sb * 16 + q];
        a0 += bf16lo(ua.x); a1 += bf16hi(ua.x);
        a2 += bf16lo(ua.y); a3 += bf16hi(ua.y);
        a0 += bf16lo(ub.x); a1 += bf16hi(ub.x);
        a2 += bf16lo(ub.y); a3 += bf16hi(ub.y);
    }
    for (; e < end; e += 4) {
        uint2 u = h2[(size_t)srt[e] * 16 + q];
        a0 += bf16lo(u.x); a1 += bf16hi(u.x);
        a2 += bf16lo(u.y); a3 += bf16hi(u.y);
    }
#pragma unroll
    for (int o = 16; o <= 32; o <<= 1) {
        a0 += __shfl_xor(a0, o, WAVE);
        a1 += __shfl_xor(a1, o, WAVE);
        a2 += __shfl_xor(a2, o, WAVE);
        a3 += __shfl_xor(a3, o, WAVE);
    }
    float wd = dinv[wid];
    float2 blo = ((const float2*)bias)[q];        // b[2q], b[2q+1]
    float2 bhi = ((const float2*)bias)[q + 16];   // b[2q+32], b[2q+33]
    float v0 = fmaf(wd, a0, blo.x);   // feat 2q
    float v2 = fmaf(wd, a2, blo.y);   // feat 2q+1
    float v1 = fmaf(wd, a1, bhi.x);   // feat 2q+32
    float v3 = fmaf(wd, a3, bhi.y);   // feat 2q+33
    float m = fmaxf(fmaxf(v0, v1), fmaxf(v2, v3));
#pragma unroll
    for (int o = 8; o; o >>= 1) m = fmaxf(m, __shfl_xor(m, o, WAVE));
    float s = __expf(v0 - m) + __expf(v1 - m) + __expf(v2 - m) + __expf(v3 - m);
#pragma unroll
    for (int o = 8; o; o >>= 1) s += __shfl_xor(s, o, WAVE);
    float lg = __logf(s) + m;
    if (quad == 0)
        *(float2*)&out[(size_t)wid * 64 + 2 * q] = make_float2(v0 - lg, v2 - lg);
    else if (quad == 1)
        *(float2*)&out[(size_t)wid * 64 + 32 + 2 * q] = make_float2(v1 - lg, v3 - lg);
}

extern "C" void kernel_launch(void* const* d_in, const int* in_sizes, int n_in,
                              void* d_out, int out_size, void* d_ws, size_t ws_size,
                              hipStream_t stream) {
    const float* x  = (const float*)d_in[0];
    const float* W1 = (const float*)d_in[1];
    const float* b1 = (const float*)d_in[2];
    const float* W2 = (const float*)d_in[3];
    const float* b2 = (const float*)d_in[4];
    const int* edge = (const int*)d_in[5];

    const int N = in_sizes[0] / 256;
    const int E = in_sizes[5] / 2;
    const int* src = edge;
    const int* dst = edge + E;

    const int NBUCK = (N + 511) >> 9;  // <=256
    int mean = E / NBUCK;
    int CAP = mean + (int)(8.5 * __builtin_sqrt((double)mean)) + 32;
    CAP = (CAP + 63) & ~63;

    // ws layout (4B units): gcnt[256] | w1f[16384] | w2f[4096] | dinv[N] | rowstart[N]
    //   | rowend[N] | sorted[NBUCK*CAP] | h1s[N*64] | h2s[N*32] | agg1bf[N*64] (pairs alias)
    int*    gcnt     = (int*)d_ws;
    uint32* w1f      = (uint32*)(gcnt + 256);
    uint32* w2f      = w1f + 16384;
    float*  dinv     = (float*)(w2f + 4096);
    int*    rowstart = (int*)(dinv + N);
    int*    rowend   = rowstart + N;
    int*    sorted   = rowend + N;
    uint32* h1s      = (uint32*)(sorted + (size_t)NBUCK * CAP);
    uint32* h2s      = h1s + (size_t)N * 64;
    uint32* agg1bf   = h2s + (size_t)N * 32;
    uint32* pairs    = agg1bf;  // dead before agg1bf is written
    float*  outp     = (float*)d_out;

    const int TB = 256;

    // 0) weight conversion to fragment-ordered bf16 (+ zero gcnt)
    convert_w_kernel<<<80, TB, 0, stream>>>(W1, W2, w1f, w2f, gcnt);

    // 1) CSR build via two-pass bucket sort (also produces dinv)
    binsort_kernel<<<(E + BIN_EPB - 1) / BIN_EPB, BIN_TB, 0, stream>>>(src, dst, gcnt, pairs, E, CAP);
    bucket_csr_kernel<<<NBUCK, 512, 0, stream>>>(pairs, gcnt, sorted, rowstart, rowend, dinv, N, CAP);

    // 2) h1s = bf16(dinv * (x @ W1))  [MFMA]
    gemm1_mfma<<<(N + 127) / 128, TB, 0, stream>>>(x, w1f, dinv, h1s, N);

    // 3) agg1bf = bf16(relu(dinv[d]*(self+sum) + b1)), natural feature order
    agg1_kernel<<<(N * 64 + TB - 1) / TB, TB, 0, stream>>>(h1s, dinv, sorted, rowstart, rowend, b1, agg1bf, N);

    // 4) h2s = bf16(dinv * (agg1 @ W2))  [MFMA, bf16 A direct]
    gemm2_mfma<<<(N + 127) / 128, TB, 0, stream>>>(agg1bf, w2f, dinv, h2s, N);

    // 5) out = log_softmax(dinv[d]*(self+sum) + b2)
    agg2_ls_kernel<<<(N * 64 + TB - 1) / TB, TB, 0, stream>>>(h2s, dinv, sorted, rowstart, rowend, b2, outp, N);
}

// Round 7
// 268.762 us; speedup vs baseline: 9.3013x; 1.1199x over previous
//
#include <hip/hip_runtime.h>
#include <hip/hip_bf16.h>

#define WAVE 64
typedef unsigned int uint32;
typedef __attribute__((ext_vector_type(8))) short bf16x8;
typedef __attribute__((ext_vector_type(4))) float f32x4;

// ---- bf16 helpers ----
__device__ inline float bf16lo(uint32 u) { return __uint_as_float(u << 16); }
__device__ inline float bf16hi(uint32 u) { return __uint_as_float(u & 0xffff0000u); }
__device__ inline uint32 f2bf(float f) {  // round-to-nearest-even, bits in low 16
    union { float f; uint32 u; } a; a.f = f;
    uint32 u = a.u;
    u += 0x7fffu + ((u >> 16) & 1u);
    return u >> 16;
}
__device__ inline uint32 packbf(float lo, float hi) { return f2bf(lo) | (f2bf(hi) << 16); }
__device__ inline short f2bfs(float f) { return (short)f2bf(f); }

// ---------------- W1/W2 -> fragment-ordered bf16 (+ gcnt zeroing) ----------------
__global__ void convert_w_kernel(const float* __restrict__ W1, const float* __restrict__ W2,
                                 uint32* __restrict__ w1f, uint32* __restrict__ w2f,
                                 int* __restrict__ gcnt) {
    int tid = blockIdx.x * blockDim.x + threadIdx.x;  // 0..20479
    if (tid < 256) gcnt[tid] = 0;
    if (tid < 16384) {
        int w = tid & 3, l = (tid >> 2) & 63, c = (tid >> 8) & 7, kc = tid >> 11;
        int q = l & 15, g = l >> 4;
        int k0 = kc * 32 + g * 8 + 2 * w;
        int n = c * 16 + q;
        w1f[tid] = packbf(W1[k0 * 128 + n], W1[(k0 + 1) * 128 + n]);
    } else if (tid < 16384 + 4096) {
        int t = tid - 16384;
        int w = t & 3, l = (t >> 2) & 63, c = (t >> 8) & 3, kc = t >> 10;
        int q = l & 15, g = l >> 4;
        int k0 = kc * 32 + g * 8 + 2 * w;
        int n = c * 16 + q;
        w2f[t] = packbf(W2[k0 * 64 + n], W2[(k0 + 1) * 64 + n]);
    }
}

// ================= CSR build: two-pass bucket sort =================
// Bucket = dst >> 9 (512 nodes per bucket). NBUCK <= 256.
#define BIN_TB 1024
#define BIN_EPB 4096
// Pass B: LDS-staged bucket sort of 4096 edges, coalesced flush to bucket regions.
__global__ __launch_bounds__(BIN_TB) void binsort_kernel(const int* __restrict__ src,
                                                         const int* __restrict__ dst,
                                                         int* __restrict__ gcnt,
                                                         uint32* __restrict__ pairs,
                                                         int E, int CAP) {
    __shared__ int hist[256];
    __shared__ int scan[256];
    __shared__ int lstart[256];
    __shared__ int gbase[256];
    __shared__ int lcur[256];
    __shared__ uint32 sp[BIN_EPB];
    __shared__ unsigned char sb[BIN_EPB];
    int tid = threadIdx.x;
    int base = blockIdx.x * BIN_EPB;
    if (tid < 256) hist[tid] = 0;
    __syncthreads();
    int s[4], b[4];
    uint32 pk[4];
    bool v[4];
#pragma unroll
    for (int j = 0; j < 4; ++j) {
        int e = base + tid + j * BIN_TB;
        v[j] = e < E;
        if (v[j]) {
            s[j] = src[e];
            int d = dst[e];
            b[j] = d >> 9;
            pk[j] = (uint32)s[j] | ((uint32)(d & 511) << 17);
            atomicAdd(&hist[b[j]], 1);
        }
    }
    __syncthreads();
    // exclusive scan of hist (256 wide)
    if (tid < 256) scan[tid] = hist[tid];
    __syncthreads();
#pragma unroll
    for (int o = 1; o < 256; o <<= 1) {
        int t = 0;
        if (tid < 256 && tid >= o) t = scan[tid - o];
        __syncthreads();
        if (tid < 256) scan[tid] += t;
        __syncthreads();
    }
    if (tid < 256) {
        int st = scan[tid] - hist[tid];
        lstart[tid] = st;
        lcur[tid] = st;
        gbase[tid] = (hist[tid] > 0) ? (tid * CAP + atomicAdd(&gcnt[tid], hist[tid])) : 0;
    }
    __syncthreads();
    // LDS scatter (bucket-sorted staging)
#pragma unroll
    for (int j = 0; j < 4; ++j) {
        if (v[j]) {
            int p = atomicAdd(&lcur[b[j]], 1);
            sp[p] = pk[j];
            sb[p] = (unsigned char)b[j];
        }
    }
    __syncthreads();
    // coalesced flush: consecutive slots in a bucket -> consecutive global addresses
    int total = scan[255];
    for (int i = tid; i < total; i += BIN_TB) {
        int bb = sb[i];
        pairs[gbase[bb] + (i - lstart[bb])] = sp[i];
    }
}

// Pass C: per-bucket counting sort staged in dynamic LDS, coalesced flush.
__global__ __launch_bounds__(512) void bucket_csr_kernel(const uint32* __restrict__ pairs,
                                                         const int* __restrict__ gcnt,
                                                         int* __restrict__ sorted,
                                                         int* __restrict__ rowstart,
                                                         int* __restrict__ rowend,
                                                         float* __restrict__ dinv,
                                                         int N, int CAP) {
    __shared__ int cnt[512];
    __shared__ int incl[512];
    __shared__ int cursor[512];
    extern __shared__ uint32 ssorted[];  // CAP entries
    int b = blockIdx.x;
    int tid = threadIdx.x;
    int ne = gcnt[b];
    if (ne > CAP) ne = CAP;
    const uint32* P = pairs + (size_t)b * CAP;
    cnt[tid] = 0;
    __syncthreads();
    for (int i = tid; i < ne; i += 512) atomicAdd(&cnt[P[i] >> 17], 1);
    __syncthreads();
    int v = cnt[tid];
    incl[tid] = v;
    __syncthreads();
#pragma unroll
    for (int o = 1; o < 512; o <<= 1) {
        int t = (tid >= o) ? incl[tid - o] : 0;
        __syncthreads();
        incl[tid] += t;
        __syncthreads();
    }
    int gbase = b * CAP;
    int node = b * 512 + tid;
    if (node < N) {
        rowstart[node] = gbase + incl[tid] - v;
        rowend[node] = gbase + incl[tid];
        dinv[node] = rsqrtf(1.0f + (float)v);
    }
    cursor[tid] = incl[tid] - v;
    __syncthreads();
    // place into LDS (fast scattered LDS writes)
    for (int i = tid; i < ne; i += 512) {
        uint32 p = P[i];
        int ln = p >> 17;
        int r = atomicAdd(&cursor[ln], 1);
        ssorted[r] = p & 0x1FFFFu;
    }
    __syncthreads();
    // coalesced flush
    for (int i = tid; i < ne; i += 512) sorted[gbase + i] = (int)ssorted[i];
}

// ---------------- GEMM1 (MFMA): [N,256]fp32 @ W1F -> h1s bf16 pairs (f, f+64) ----------------
__global__ __launch_bounds__(256) void gemm1_mfma(const float* __restrict__ x,
                                                  const uint32* __restrict__ w1f,
                                                  const float* __restrict__ dinv,
                                                  uint32* __restrict__ hout,  // N x 64
                                                  int N) {
    const bf16x8* Bp = (const bf16x8*)w1f;
    int l = threadIdx.x & 63, w = threadIdx.x >> 6;
    int q = l & 15, g = l >> 4;
    int R = blockIdx.x * 128 + w * 32;
    f32x4 acc[2][8];
#pragma unroll
    for (int rt = 0; rt < 2; ++rt)
#pragma unroll
        for (int c = 0; c < 8; ++c) acc[rt][c] = (f32x4){0.f, 0.f, 0.f, 0.f};

#pragma unroll
    for (int kc = 0; kc < 8; ++kc) {
        bf16x8 b[8];
#pragma unroll
        for (int c = 0; c < 8; ++c) b[c] = Bp[(kc * 8 + c) * 64 + l];
#pragma unroll
        for (int rt = 0; rt < 2; ++rt) {
            int row = R + rt * 16 + q;
            row = row < N ? row : N - 1;
            const float* xr = x + (size_t)row * 256 + kc * 32 + g * 8;
            float4 xa = *(const float4*)xr;
            float4 xb = *(const float4*)(xr + 4);
            bf16x8 a;
            a[0] = f2bfs(xa.x); a[1] = f2bfs(xa.y); a[2] = f2bfs(xa.z); a[3] = f2bfs(xa.w);
            a[4] = f2bfs(xb.x); a[5] = f2bfs(xb.y); a[6] = f2bfs(xb.z); a[7] = f2bfs(xb.w);
#pragma unroll
            for (int c = 0; c < 8; ++c)
                acc[rt][c] = __builtin_amdgcn_mfma_f32_16x16x32_bf16(a, b[c], acc[rt][c], 0, 0, 0);
        }
    }
#pragma unroll
    for (int rt = 0; rt < 2; ++rt)
#pragma unroll
        for (int r = 0; r < 4; ++r) {
            int grow = R + rt * 16 + 4 * g + r;
            if (grow < N) {
                float wd = dinv[grow];
                uint32* orow = hout + (size_t)grow * 64;
#pragma unroll
                for (int c = 0; c < 4; ++c)
                    orow[c * 16 + q] = packbf(acc[rt][c][r] * wd, acc[rt][c + 4][r] * wd);
            }
        }
}

// ---------------- layer-1 pull aggregation: uint2 loads, 8 edges in flight ----------------
__global__ __launch_bounds__(256) void agg1_kernel(const uint32* __restrict__ h,  // N x 64
                                                   const float* __restrict__ dinv,
                                                   const int* __restrict__ srt,
                                                   const int* __restrict__ rowstart,
                                                   const int* __restrict__ rowend,
                                                   const float* __restrict__ bias,
                                                   uint32* __restrict__ out,  // N x 64 bf16-pairs
                                                   int n) {
    int wid = (int)(((long)blockIdx.x * blockDim.x + threadIdx.x) >> 6);
    int lane = threadIdx.x & 63;
    if (wid >= n) return;
    const uint2* h2 = (const uint2*)h;
    int q = lane & 31;
    int half = lane >> 5;
    int start = rowstart[wid];
    int end = rowend[wid];
    float a0 = 0.f, a1 = 0.f, a2 = 0.f, a3 = 0.f;
    if (half == 0) {  // self (already dinv-scaled)
        uint2 us = h2[(size_t)wid * 32 + q];
        a0 = bf16lo(us.x); a1 = bf16hi(us.x);
        a2 = bf16lo(us.y); a3 = bf16hi(us.y);
    }
    int e = start + half;
    for (; e + 6 < end; e += 8) {  // 4 gathers in flight per half-wave
        int s0 = srt[e], s1 = srt[e + 2], s2 = srt[e + 4], s3 = srt[e + 6];
        uint2 u0 = h2[(size_t)s0 * 32 + q];
        uint2 u1 = h2[(size_t)s1 * 32 + q];
        uint2 u2 = h2[(size_t)s2 * 32 + q];
        uint2 u3 = h2[(size_t)s3 * 32 + q];
        a0 += bf16lo(u0.x); a1 += bf16hi(u0.x); a2 += bf16lo(u0.y); a3 += bf16hi(u0.y);
        a0 += bf16lo(u1.x); a1 += bf16hi(u1.x); a2 += bf16lo(u1.y); a3 += bf16hi(u1.y);
        a0 += bf16lo(u2.x); a1 += bf16hi(u2.x); a2 += bf16lo(u2.y); a3 += bf16hi(u2.y);
        a0 += bf16lo(u3.x); a1 += bf16hi(u3.x); a2 += bf16lo(u3.y); a3 += bf16hi(u3.y);
    }
    for (; e < end; e += 2) {
        uint2 u = h2[(size_t)srt[e] * 32 + q];
        a0 += bf16lo(u.x); a1 += bf16hi(u.x);
        a2 += bf16lo(u.y); a3 += bf16hi(u.y);
    }
    a0 += __shfl_xor(a0, 32, WAVE);
    a1 += __shfl_xor(a1, 32, WAVE);
    a2 += __shfl_xor(a2, 32, WAVE);
    a3 += __shfl_xor(a3, 32, WAVE);
    float wd = dinv[wid];
    float2 blo = ((const float2*)bias)[q];        // b[2q], b[2q+1]
    float2 bhi = ((const float2*)bias)[q + 32];   // b[2q+64], b[2q+65]
    float v0 = fmaxf(fmaf(wd, a0, blo.x), 0.f);   // feat 2q
    float v2 = fmaxf(fmaf(wd, a2, blo.y), 0.f);   // feat 2q+1
    float v1 = fmaxf(fmaf(wd, a1, bhi.x), 0.f);   // feat 2q+64
    float v3 = fmaxf(fmaf(wd, a3, bhi.y), 0.f);   // feat 2q+65
    uint32* orow = out + (size_t)wid * 64;
    if (half == 0) orow[q] = packbf(v0, v2);
    else           orow[q + 32] = packbf(v1, v3);
}

// ---------------- GEMM2 (MFMA): [N,128]bf16 @ W2F -> h2s bf16 pairs (f, f+32) ----------------
__global__ __launch_bounds__(256) void gemm2_mfma(const uint32* __restrict__ hin,  // N x 64 bf16-pairs
                                                  const uint32* __restrict__ w2f,
                                                  const float* __restrict__ dinv,
                                                  uint32* __restrict__ hout,  // N x 32
                                                  int N) {
    const bf16x8* Bp = (const bf16x8*)w2f;
    const short* hs = (const short*)hin;
    int l = threadIdx.x & 63, w = threadIdx.x >> 6;
    int q = l & 15, g = l >> 4;
    int R = blockIdx.x * 128 + w * 32;
    f32x4 acc[2][4];
#pragma unroll
    for (int rt = 0; rt < 2; ++rt)
#pragma unroll
        for (int c = 0; c < 4; ++c) acc[rt][c] = (f32x4){0.f, 0.f, 0.f, 0.f};

#pragma unroll
    for (int kc = 0; kc < 4; ++kc) {
        bf16x8 b[4];
#pragma unroll
        for (int c = 0; c < 4; ++c) b[c] = Bp[(kc * 4 + c) * 64 + l];
#pragma unroll
        for (int rt = 0; rt < 2; ++rt) {
            int row = R + rt * 16 + q;
            row = row < N ? row : N - 1;
            bf16x8 a = *(const bf16x8*)(hs + (size_t)row * 128 + kc * 32 + g * 8);
#pragma unroll
            for (int c = 0; c < 4; ++c)
                acc[rt][c] = __builtin_amdgcn_mfma_f32_16x16x32_bf16(a, b[c], acc[rt][c], 0, 0, 0);
        }
    }
#pragma unroll
    for (int rt = 0; rt < 2; ++rt)
#pragma unroll
        for (int r = 0; r < 4; ++r) {
            int grow = R + rt * 16 + 4 * g + r;
            if (grow < N) {
                float wd = dinv[grow];
                uint32* orow = hout + (size_t)grow * 32;
#pragma unroll
                for (int c = 0; c < 2; ++c)
                    orow[c * 16 + q] = packbf(acc[rt][c][r] * wd, acc[rt][c + 2][r] * wd);
            }
        }
}

// ---------------- layer-2 pull aggregation + log_softmax: uint2 loads, 16 edges in flight ----------------
__global__ __launch_bounds__(256) void agg2_ls_kernel(const uint32* __restrict__ h,  // N x 32
                                                      const float* __restrict__ dinv,
                                                      const int* __restrict__ srt,
                                                      const int* __restrict__ rowstart,
                                                      const int* __restrict__ rowend,
                                                      const float* __restrict__ bias,
                                                      float* __restrict__ out, int n) {
    int wid = (int)(((long)blockIdx.x * blockDim.x + threadIdx.x) >> 6);
    int lane = threadIdx.x & 63;
    if (wid >= n) return;
    const uint2* h2 = (const uint2*)h;
    int q = lane & 15;
    int quad = lane >> 4;
    int start = rowstart[wid];
    int end = rowend[wid];
    float a0 = 0.f, a1 = 0.f, a2 = 0.f, a3 = 0.f;
    if (quad == 0) {  // self
        uint2 us = h2[(size_t)wid * 16 + q];
        a0 = bf16lo(us.x); a1 = bf16hi(us.x);
        a2 = bf16lo(us.y); a3 = bf16hi(us.y);
    }
    int e = start + quad;
    for (; e + 12 < end; e += 16) {  // 4 gathers in flight per quad
        int s0 = srt[e], s1 = srt[e + 4], s2 = srt[e + 8], s3 = srt[e + 12];
        uint2 u0 = h2[(size_t)s0 * 16 + q];
        uint2 u1 = h2[(size_t)s1 * 16 + q];
        uint2 u2 = h2[(size_t)s2 * 16 + q];
        uint2 u3 = h2[(size_t)s3 * 16 + q];
        a0 += bf16lo(u0.x); a1 += bf16hi(u0.x); a2 += bf16lo(u0.y); a3 += bf16hi(u0.y);
        a0 += bf16lo(u1.x); a1 += bf16hi(u1.x); a2 += bf16lo(u1.y); a3 += bf16hi(u1.y);
        a0 += bf16lo(u2.x); a1 += bf16hi(u2.x); a2 += bf16lo(u2.y); a3 += bf16hi(u2.y);
        a0 += bf16lo(u3.x); a1 += bf16hi(u3.x); a2 += bf16lo(u3.y); a3 += bf16hi(u3.y);
    }
    for (; e < end; e += 4) {
        uint2 u = h2[(size_t)srt[e] * 16 + q];
        a0 += bf16lo(u.x); a1 += bf16hi(u.x);
        a2 += bf16lo(u.y); a3 += bf16hi(u.y);
    }
#pragma unroll
    for (int o = 16; o <= 32; o <<= 1) {
        a0 += __shfl_xor(a0, o, WAVE);
        a1 += __shfl_xor(a1, o, WAVE);
        a2 += __shfl_xor(a2, o, WAVE);
        a3 += __shfl_xor(a3, o, WAVE);
    }
    float wd = dinv[wid];
    float2 blo = ((const float2*)bias)[q];        // b[2q], b[2q+1]
    float2 bhi = ((const float2*)bias)[q + 16];   // b[2q+32], b[2q+33]
    float v0 = fmaf(wd, a0, blo.x);   // feat 2q
    float v2 = fmaf(wd, a2, blo.y);   // feat 2q+1
    float v1 = fmaf(wd, a1, bhi.x);   // feat 2q+32
    float v3 = fmaf(wd, a3, bhi.y);   // feat 2q+33
    float m = fmaxf(fmaxf(v0, v1), fmaxf(v2, v3));
#pragma unroll
    for (int o = 8; o; o >>= 1) m = fmaxf(m, __shfl_xor(m, o, WAVE));
    float s = __expf(v0 - m) + __expf(v1 - m) + __expf(v2 - m) + __expf(v3 - m);
#pragma unroll
    for (int o = 8; o; o >>= 1) s += __shfl_xor(s, o, WAVE);
    float lg = __logf(s) + m;
    if (quad == 0)
        *(float2*)&out[(size_t)wid * 64 + 2 * q] = make_float2(v0 - lg, v2 - lg);
    else if (quad == 1)
        *(float2*)&out[(size_t)wid * 64 + 32 + 2 * q] = make_float2(v1 - lg, v3 - lg);
}

extern "C" void kernel_launch(void* const* d_in, const int* in_sizes, int n_in,
                              void* d_out, int out_size, void* d_ws, size_t ws_size,
                              hipStream_t stream) {
    const float* x  = (const float*)d_in[0];
    const float* W1 = (const float*)d_in[1];
    const float* b1 = (const float*)d_in[2];
    const float* W2 = (const float*)d_in[3];
    const float* b2 = (const float*)d_in[4];
    const int* edge = (const int*)d_in[5];

    const int N = in_sizes[0] / 256;
    const int E = in_sizes[5] / 2;
    const int* src = edge;
    const int* dst = edge + E;

    const int NBUCK = (N + 511) >> 9;  // <=256
    int mean = E / NBUCK;
    int CAP = mean + (int)(8.5 * __builtin_sqrt((double)mean)) + 32;
    CAP = (CAP + 63) & ~63;
    if (CAP > 36864) CAP = 36864;  // LDS flush buffer bound (144 KB)

    // ws layout (4B units): gcnt[256] | w1f[16384] | w2f[4096] | dinv[N] | rowstart[N]
    //   | rowend[N] | sorted[NBUCK*CAP] | h1s[N*64] | h2s[N*32] | agg1bf[N*64] (pairs alias)
    int*    gcnt     = (int*)d_ws;
    uint32* w1f      = (uint32*)(gcnt + 256);
    uint32* w2f      = w1f + 16384;
    float*  dinv     = (float*)(w2f + 4096);
    int*    rowstart = (int*)(dinv + N);
    int*    rowend   = rowstart + N;
    int*    sorted   = rowend + N;
    uint32* h1s      = (uint32*)(sorted + (size_t)NBUCK * CAP);
    uint32* h2s      = h1s + (size_t)N * 64;
    uint32* agg1bf   = h2s + (size_t)N * 32;
    uint32* pairs    = agg1bf;  // dead before agg1bf is written
    float*  outp     = (float*)d_out;

    const int TB = 256;

    // 0) weight conversion to fragment-ordered bf16 (+ zero gcnt)
    convert_w_kernel<<<80, TB, 0, stream>>>(W1, W2, w1f, w2f, gcnt);

    // 1) CSR build via two-pass bucket sort (also produces dinv)
    binsort_kernel<<<(E + BIN_EPB - 1) / BIN_EPB, BIN_TB, 0, stream>>>(src, dst, gcnt, pairs, E, CAP);
    bucket_csr_kernel<<<NBUCK, 512, (size_t)CAP * 4, stream>>>(pairs, gcnt, sorted, rowstart, rowend, dinv, N, CAP);

    // 2) h1s = bf16(dinv * (x @ W1))  [MFMA]
    gemm1_mfma<<<(N + 127) / 128, TB, 0, stream>>>(x, w1f, dinv, h1s, N);

    // 3) agg1bf = bf16(relu(dinv[d]*(self+sum) + b1)), natural feature order
    agg1_kernel<<<(N * 64 + TB - 1) / TB, TB, 0, stream>>>(h1s, dinv, sorted, rowstart, rowend, b1, agg1bf, N);

    // 4) h2s = bf16(dinv * (agg1 @ W2))  [MFMA, bf16 A direct]
    gemm2_mfma<<<(N + 127) / 128, TB, 0, stream>>>(agg1bf, w2f, dinv, h2s, N);

    // 5) out = log_softmax(dinv[d]*(self+sum) + b2)
    agg2_ls_kernel<<<(N * 64 + TB - 1) / TB, TB, 0, stream>>>(h2s, dinv, sorted, rowstart, rowend, b2, outp, N);
}